// Round 13
// baseline (211.072 us; speedup 1.0000x reference)
//
#include <hip/hip_runtime.h>
#include <hip/hip_bf16.h>

#define B_ 4
#define L_ 2
#define P_ 100
#define TPP_ 64
#define D_ 768
#define G_ 10
#define T_ (P_ * TPP_)   // 6400
#define NC_ (2 * D_)     // 1536

typedef __attribute__((ext_vector_type(8))) short bf16x8;
typedef __attribute__((ext_vector_type(4))) float f32x4;

__device__ __forceinline__ unsigned short f2bf(float f) {
    __hip_bfloat16 h = __float2bfloat16(f);
    return *reinterpret_cast<unsigned short*>(&h);
}
__device__ __forceinline__ float bfu2f(unsigned short u) {
    return __uint_as_float(((unsigned int)u) << 16);
}

__device__ __forceinline__ void gload_lds16(const void* g, void* l) {
    __builtin_amdgcn_global_load_lds(
        (const __attribute__((address_space(1))) void*)g,
        (__attribute__((address_space(3))) void*)l, 16, 0, 0);
}

#define SBAR()   __builtin_amdgcn_s_barrier()
#define SCHEDB() __builtin_amdgcn_sched_barrier(0)
#define VMCNT6() asm volatile("s_waitcnt vmcnt(6)" ::: "memory")
#define VMCNT0() asm volatile("s_waitcnt vmcnt(0)" ::: "memory")

// ---------------------------------------------------------------------------
// 128x256 tile, 8 waves (512 thr), BK=64.  Both-sides 8x16B-slot swizzle
// (validated r6-r12): LDS[r][s] = G[r][s ^ (r&7)]; read slot = gs ^ (r&7).
// Per thread per K-tile: 2 A-loads + 4 B-loads = 6  ->  vmcnt(6) steady state.
// ---------------------------------------------------------------------------
__device__ __forceinline__ void stage256(
    const __hip_bfloat16* __restrict__ Ag, const __hip_bfloat16* __restrict__ Bg,
    int k0, __hip_bfloat16 (*As)[64], __hip_bfloat16 (*Bs)[64],
    int w, int row_l, int soff)
{
#pragma unroll
    for (int j = 0; j < 2; ++j) {   // A: 128 rows, wave covers 16
        int r = w * 16 + j * 8 + row_l;
        gload_lds16(Ag + (size_t)r * D_ + k0 + soff, &As[w * 16 + j * 8][0]);
    }
#pragma unroll
    for (int j = 0; j < 4; ++j) {   // B: 256 rows, wave covers 32
        int r = w * 32 + j * 8 + row_l;
        gload_lds16(Bg + (size_t)r * D_ + k0 + soff, &Bs[w * 32 + j * 8][0]);
    }
}

// Fragment-read + 32 MFMA per call.  Works for any wm/wn range (row count is
// not part of the pointer type) — shared by the 2m x 4n geometry.
__device__ __forceinline__ void mfma_step64(
    __hip_bfloat16 (*As)[64], __hip_bfloat16 (*Bs)[64],
    int rr, int h, int wm, int wn, f32x4 acc[4][4])
{
#pragma unroll
    for (int ks = 0; ks < 2; ++ks) {
        const int rsl = (((ks << 2) + h) ^ (rr & 7)) << 3;
        bf16x8 af[4], bfr[4];
#pragma unroll
        for (int mi = 0; mi < 4; ++mi)
            af[mi] = *reinterpret_cast<const bf16x8*>(
                &As[wm * 64 + mi * 16 + rr][rsl]);
#pragma unroll
        for (int ni = 0; ni < 4; ++ni)
            bfr[ni] = *reinterpret_cast<const bf16x8*>(
                &Bs[wn * 64 + ni * 16 + rr][rsl]);
#pragma unroll
        for (int mi = 0; mi < 4; ++mi)
#pragma unroll
            for (int ni = 0; ni < 4; ++ni)
                acc[mi][ni] = __builtin_amdgcn_mfma_f32_16x16x32_bf16(
                    af[mi], bfr[ni], acc[mi][ni], 0, 0, 0);
    }
}

#define MFMA_STEP_P(As, Bs)                                                   \
    __builtin_amdgcn_s_setprio(1);                                            \
    mfma_step64(As, Bs, rr, h, wm, wn, acc);                                  \
    __builtin_amdgcn_s_setprio(0);

// T4 counted-vmcnt pipeline (structure validated r9/r12), 512-thread variant.
#define MFMA_LOOP_PIPE(Ag, Bg)                                                \
    {                                                                         \
        const int rr = lane & 15, h = lane >> 4;                              \
        const int row_l = lane >> 3;                                          \
        const int soff = ((lane & 7) ^ row_l) << 3;                           \
        stage256((Ag), (Bg), 0, As0, Bs0, w, row_l, soff);                    \
        stage256((Ag), (Bg), 64, As1, Bs1, w, row_l, soff);                   \
        SCHEDB();                                                             \
        for (int t = 0; t < 10; t += 2) {                                     \
            VMCNT6(); SBAR(); SCHEDB();                                       \
            MFMA_STEP_P(As0, Bs0);                                            \
            SCHEDB(); SBAR(); SCHEDB();                                       \
            stage256((Ag), (Bg), (t + 2) * 64, As0, Bs0, w, row_l, soff);     \
            SCHEDB();                                                         \
            VMCNT6(); SBAR(); SCHEDB();                                       \
            MFMA_STEP_P(As1, Bs1);                                            \
            SCHEDB(); SBAR(); SCHEDB();                                       \
            stage256((Ag), (Bg), (t + 3) * 64, As1, Bs1, w, row_l, soff);     \
            SCHEDB();                                                         \
        }                                                                     \
        VMCNT6(); SBAR(); SCHEDB();                                           \
        MFMA_STEP_P(As0, Bs0);                        /* tile 10 */           \
        SCHEDB();                                                             \
        VMCNT0(); SBAR(); SCHEDB();                                           \
        MFMA_STEP_P(As1, Bs1);                        /* tile 11 */           \
        __syncthreads();                                                      \
    }

#define DECL_LDS_DB()                                                         \
    __shared__ __align__(16) __hip_bfloat16 As0[128][64];  /* 16 KB */        \
    __shared__ __align__(16) __hip_bfloat16 Bs0[256][64];  /* 32 KB */        \
    __shared__ __align__(16) __hip_bfloat16 As1[128][64];                     \
    __shared__ __align__(16) __hip_bfloat16 Bs1[256][64];  /* total 96 KB */

#define DECL_ACC()                                                            \
    f32x4 acc[4][4];                                                          \
    _Pragma("unroll") for (int i = 0; i < 4; ++i)                             \
        _Pragma("unroll") for (int j = 0; j < 4; ++j)                         \
            _Pragma("unroll") for (int e = 0; e < 4; ++e) acc[i][j][e] = 0.0f;

// ---------------------------------------------------------------------------
// P-ALL (validated r9): wct / const / w1t / groups / out_init / conv_q fused.
// ---------------------------------------------------------------------------
__global__ __launch_bounds__(256) void prep_all(
    const float* __restrict__ answer, const float* __restrict__ W_p,
    const float* __restrict__ b_p, const float* __restrict__ W_t,
    const float* __restrict__ b_t, const float* __restrict__ W1,
    const float* __restrict__ qps, const int* __restrict__ tids,
    const float* __restrict__ mask, const float* __restrict__ b2,
    __hip_bfloat16* __restrict__ Wpe_nat, __hip_bfloat16* __restrict__ Wbig,
    float* __restrict__ c_p, float* __restrict__ c_t,
    __hip_bfloat16* __restrict__ qb, __hip_bfloat16* __restrict__ W1at,
    __hip_bfloat16* __restrict__ W1bt, int* __restrict__ glist,
    int* __restrict__ goff, float* __restrict__ out)
{
    __shared__ float lds[64][65];
    __shared__ float a_s[64];
    __shared__ float red2[2][4][64];
    __shared__ int g_cnt[B_][G_];
    __shared__ int g_off[B_][G_ + 1];
    __shared__ int g_cur[B_][G_];

    const int bid = blockIdx.x;
    const int tid = threadIdx.x;

    if (bid < 1152) {
        const int n0 = (bid % 24) * 64;
        const int k0 = ((bid / 24) % 12) * 64;
        const int b  = bid / 288;
        if (tid < 64) a_s[tid] = answer[((size_t)b * L_ + (L_ - 1)) * D_ + k0 + tid];
        __syncthreads();
        if (n0 < D_) {
#pragma unroll
            for (int i = 0; i < 16; ++i) {
                int k = (tid >> 6) + i * 4;
                int n = tid & 63;
                float v = W_p[(size_t)(D_ + k0 + k) * D_ + n0 + n] +
                          a_s[k] * W_p[(size_t)(2 * D_ + k0 + k) * D_ + n0 + n];
                Wpe_nat[(size_t)b * D_ * D_ + (size_t)(k0 + k) * D_ + n0 + n] =
                    __float2bfloat16(v);
            }
        } else {
            const int nn0 = n0 - D_;
#pragma unroll
            for (int i = 0; i < 16; ++i) {
                int k = (tid >> 6) + i * 4;
                int n = tid & 63;
                lds[k][n] = W_t[(size_t)(D_ + k0 + k) * D_ + nn0 + n] +
                            a_s[k] * W_t[(size_t)(2 * D_ + k0 + k) * D_ + nn0 + n];
            }
            __syncthreads();
#pragma unroll
            for (int j = 0; j < 16; ++j) {
                int n = (tid >> 6) + j * 4;
                int kk = tid & 63;
                Wbig[((size_t)b * NC_ + n0 + n) * D_ + k0 + kk] =
                    __float2bfloat16(lds[kk][n]);
            }
        }
    } else if (bid < 1200) {
        const int local = bid - 1152;
        const int b = local / 12;
        const int d = (local % 12) * 64 + (tid & 63);
        const int ks = tid >> 6;
        const float* a = answer + ((size_t)b * L_ + (L_ - 1)) * D_;
        float sp = 0.f, st = 0.f;
#pragma unroll 4
        for (int k = ks; k < D_; k += 4) {
            float av = a[k];
            sp += av * W_p[(size_t)k * D_ + d];
            st += av * W_t[(size_t)k * D_ + d];
        }
        red2[0][ks][tid & 63] = sp;
        red2[1][ks][tid & 63] = st;
        __syncthreads();
        if (ks == 0) {
            float s1 = b_p[d], s2 = b_t[d];
#pragma unroll
            for (int i = 0; i < 4; ++i) {
                s1 += red2[0][i][tid & 63];
                s2 += red2[1][i][tid & 63];
            }
            c_p[b * D_ + d] = s1;
            c_t[b * D_ + d] = s2;
        }
    } else if (bid < 1488) {
        const int local = bid - 1200;
        const int n0 = (local % 12) * 64;
        const int k0 = (local / 12) * 64;
#pragma unroll
        for (int i = 0; i < 16; ++i) {
            int k = (tid >> 6) + i * 4;
            int n = tid & 63;
            lds[k][n] = W1[(size_t)(k0 + k) * D_ + n0 + n];
        }
        __syncthreads();
        __hip_bfloat16* dst = (k0 < D_) ? W1at : W1bt;
        const int kk0 = (k0 < D_) ? k0 : k0 - D_;
#pragma unroll
        for (int j = 0; j < 16; ++j) {
            int n = (tid >> 6) + j * 4;
            int kk = tid & 63;
            dst[(size_t)(n0 + n) * D_ + kk0 + kk] = __float2bfloat16(lds[kk][n]);
        }
    } else if (bid == 1488) {
        if (tid < B_ * G_) g_cnt[tid / G_][tid % G_] = 0;
        __syncthreads();
        for (int i = tid; i < B_ * P_; i += 256)
            atomicAdd(&g_cnt[i / P_][tids[i]], 1);
        __syncthreads();
        if (tid < B_) {
            int o = 0;
            for (int g = 0; g < G_; ++g) { g_off[tid][g] = o; o += g_cnt[tid][g]; }
            g_off[tid][G_] = o;
            for (int g = 0; g <= G_; ++g) goff[tid * (G_ + 1) + g] = g_off[tid][g];
        }
        __syncthreads();
        if (tid < B_ * G_) g_cur[tid / G_][tid % G_] = g_off[tid / G_][tid % G_];
        __syncthreads();
        for (int i = tid; i < B_ * P_; i += 256) {
            int b = i / P_, p = i % P_;
            int slot = atomicAdd(&g_cur[b][tids[i]], 1);
            glist[b * P_ + slot] = p;
        }
    } else if (bid < 1491) {
        int bp = (bid - 1489) * 256 + tid;
        if (bp < B_ * P_) {
            float s = 0.f;
#pragma unroll 8
            for (int t = 0; t < TPP_; ++t) s += mask[(size_t)bp * TPP_ + t];
            out[bp] = s * b2[0];
        }
    } else {
        size_t base = ((size_t)(bid - 1491) * 256 + tid) * 8;
        int b = (int)(base / ((size_t)T_ * D_));
        size_t off = base % ((size_t)T_ * D_);
        const float4* src = reinterpret_cast<const float4*>(
            qps + ((size_t)b * L_ + (L_ - 1)) * (size_t)T_ * D_ + off);
        float4 v0 = src[0], v1 = src[1];
        bf16x8 o;
        o[0] = (short)f2bf(v0.x); o[1] = (short)f2bf(v0.y);
        o[2] = (short)f2bf(v0.z); o[3] = (short)f2bf(v0.w);
        o[4] = (short)f2bf(v1.x); o[5] = (short)f2bf(v1.y);
        o[6] = (short)f2bf(v1.z); o[7] = (short)f2bf(v1.w);
        *reinterpret_cast<bf16x8*>(&qb[base]) = o;
    }
}

// ---------------------------------------------------------------------------
// FUSED K2 (512 thr): [0,600) ts (128x256, XCD-swizzled); [600,672) gemm_c1
// (128x256); [672,720) prep_cc (8-way K split).
// ---------------------------------------------------------------------------
__global__ __launch_bounds__(512) void fused_ts_c1(
    const __hip_bfloat16* __restrict__ qb, __hip_bfloat16* __restrict__ Wbig,
    const float* __restrict__ c_t, __hip_bfloat16* __restrict__ ts,
    const __hip_bfloat16* __restrict__ W1at,
    const __hip_bfloat16* __restrict__ Wpe_nat,
    const float* __restrict__ c_p, const float* __restrict__ W1,
    const float* __restrict__ b1, float* __restrict__ cc)
{
    DECL_LDS_DB();
    __shared__ float red[8][64];
    const int bid = blockIdx.x;
    const int tid = threadIdx.x;
    const int lane = tid & 63, w = tid >> 6;
    const int wm = w & 1, wn = w >> 1;   // 2m x 4n

    if (bid < 600) {
        const int swz = (bid & 7) * 75 + (bid >> 3);   // 600 = 8*75
        const int tn = swz % 3;
        const int tmb = swz / 3;
        const int tm = tmb % 50, b = tmb / 50;
        DECL_ACC();
        const __hip_bfloat16* Ag = qb + (size_t)b * T_ * D_ + (size_t)tm * 128 * D_;
        const __hip_bfloat16* Bg =
            Wbig + (size_t)b * NC_ * D_ + (size_t)(D_ + tn * 256) * D_;
        MFMA_LOOP_PIPE(Ag, Bg);
#pragma unroll
        for (int mi = 0; mi < 4; ++mi)
#pragma unroll
            for (int ni = 0; ni < 4; ++ni) {
                int col = tn * 256 + wn * 64 + ni * 16 + (lane & 15);
                int rb  = tm * 128 + wm * 64 + mi * 16 + (lane >> 4) * 4;
                float cv = c_t[b * D_ + col];
#pragma unroll
                for (int e = 0; e < 4; ++e)
                    ts[((size_t)b * T_ + rb + e) * D_ + col] =
                        __float2bfloat16(acc[mi][ni][e] + cv);
            }
    } else if (bid < 672) {
        const int local = bid - 600;                   // 72 = 6 tm x 3 tn x 4 b
        const int tm = local % 6, tn = (local / 6) % 3, b = local / 18;
        DECL_ACC();
        const __hip_bfloat16* Ag = W1at + (size_t)tm * 128 * D_;
        const __hip_bfloat16* Bg =
            Wpe_nat + (size_t)b * D_ * D_ + (size_t)tn * 256 * D_;
        MFMA_LOOP_PIPE(Ag, Bg);
#pragma unroll
        for (int mi = 0; mi < 4; ++mi)
#pragma unroll
            for (int ni = 0; ni < 4; ++ni) {
                int col = tn * 256 + wn * 64 + ni * 16 + (lane & 15);
                int row = tm * 128 + wm * 64 + mi * 16 + (lane >> 4) * 4;
#pragma unroll
                for (int e = 0; e < 4; ++e)
                    Wbig[(size_t)b * NC_ * D_ + (size_t)(row + e) * D_ + col] =
                        __float2bfloat16(acc[mi][ni][e]);
            }
    } else {
        const int local = bid - 672;                   // 48 = 4 b x 12 n-blocks
        const int b = local / 12;
        const int n = (local % 12) * 64 + (tid & 63);
        const int ks = tid >> 6;                       // 0..7
        float s = 0.f;
#pragma unroll 4
        for (int d = ks; d < D_; d += 8)
            s += c_p[b * D_ + d] * W1[(size_t)d * D_ + n];
        red[ks][tid & 63] = s;
        __syncthreads();
        if (ks == 0) {
            float tot = b1[n];
#pragma unroll
            for (int i = 0; i < 8; ++i) tot += red[i][tid & 63];
            cc[b * D_ + n] = tot;
        }
    }
}

// ---------------------------------------------------------------------------
// K3: segment max via group lists; 4 d's per thread
// ---------------------------------------------------------------------------
__global__ __launch_bounds__(256) void segmax_kernel(
    const __hip_bfloat16* __restrict__ ts, const int* __restrict__ glist,
    const int* __restrict__ goff, __hip_bfloat16* __restrict__ sm)
{
    int idx = blockIdx.x * 256 + threadIdx.x;
    int d4 = idx % (D_ / 4);
    int bt = idx / (D_ / 4);
    int t = bt % TPP_;
    int b = bt / TPP_;

    const ushort4* base =
        reinterpret_cast<const ushort4*>(ts + ((size_t)b * T_ + t) * D_) + d4;

    for (int g = 0; g < G_; ++g) {
        float m0 = -1e30f, m1 = -1e30f, m2 = -1e30f, m3 = -1e30f;
        int i0 = goff[b * (G_ + 1) + g], i1 = goff[b * (G_ + 1) + g + 1];
        for (int i = i0; i < i1; ++i) {
            int p = glist[b * P_ + i];
            ushort4 u = base[(size_t)p * TPP_ * (D_ / 4)];
            m0 = fmaxf(m0, bfu2f(u.x));
            m1 = fmaxf(m1, bfu2f(u.y));
            m2 = fmaxf(m2, bfu2f(u.z));
            m3 = fmaxf(m3, bfu2f(u.w));
        }
        ushort4 o;
        o.x = f2bf(m0); o.y = f2bf(m1); o.z = f2bf(m2); o.w = f2bf(m3);
        reinterpret_cast<ushort4*>(
            sm + (((size_t)b * G_ + g) * TPP_ + t) * D_)[d4] = o;
    }
}

// ---------------------------------------------------------------------------
// K4: smW = sm @ W1bt^T  (60 blocks: 20 tm x 3 tn, 128x256, 512 thr)
// ---------------------------------------------------------------------------
__global__ __launch_bounds__(512) void gemm_smw(
    const __hip_bfloat16* __restrict__ sm, const __hip_bfloat16* __restrict__ W1bt,
    __hip_bfloat16* __restrict__ smW)
{
    const int tn = blockIdx.x % 3, tm = blockIdx.x / 3;
    DECL_LDS_DB();
    const int tid = threadIdx.x;
    const int lane = tid & 63, w = tid >> 6;
    const int wm = w & 1, wn = w >> 1;
    DECL_ACC();

    const __hip_bfloat16* Ag = sm + (size_t)tm * 128 * D_;
    const __hip_bfloat16* Bg = W1bt + (size_t)tn * 256 * D_;
    MFMA_LOOP_PIPE(Ag, Bg);

#pragma unroll
    for (int mi = 0; mi < 4; ++mi)
#pragma unroll
        for (int ni = 0; ni < 4; ++ni) {
            int col = tn * 256 + wn * 64 + ni * 16 + (lane & 15);
            int rb  = tm * 128 + wm * 64 + mi * 16 + (lane >> 4) * 4;
#pragma unroll
            for (int e = 0; e < 4; ++e)
                smW[(size_t)(rb + e) * D_ + col] = __float2bfloat16(acc[mi][ni][e]);
        }
}

// ---------------------------------------------------------------------------
// K5: fused  acc = qb @ Wbig[b][0..768]^T ; v = relu(acc + cc + smW[g])
//     rowdot = v . W2 ; out[b][p] += sum_t mask * rowdot
//     600 blocks (128x256), XCD-swizzled, rowsum over 4 wn-groups.
// ---------------------------------------------------------------------------
__global__ __launch_bounds__(512) void gemm_fin(
    const __hip_bfloat16* __restrict__ qb, const __hip_bfloat16* __restrict__ Wbig,
    const float* __restrict__ cc, const __hip_bfloat16* __restrict__ smW,
    const int* __restrict__ tids, const float* __restrict__ W2,
    const float* __restrict__ mask, float* __restrict__ out)
{
    const int swz = (blockIdx.x & 7) * 75 + (blockIdx.x >> 3);
    const int tn = swz % 3;
    const int tmb = swz / 3;
    const int tm = tmb % 50, b = tmb / 50;
    DECL_LDS_DB();
    __shared__ float rowsum[4][128];

    const int tid = threadIdx.x;
    const int lane = tid & 63, w = tid >> 6;
    const int wm = w & 1, wn = w >> 1;
    DECL_ACC();

    const __hip_bfloat16* Ag = qb + (size_t)b * T_ * D_ + (size_t)tm * 128 * D_;
    const __hip_bfloat16* Bg = Wbig + (size_t)b * NC_ * D_ + (size_t)tn * 256 * D_;
    MFMA_LOOP_PIPE(Ag, Bg);

    const int p = tm * 2 + wm;
    const int g = tids[b * P_ + p];
    const __hip_bfloat16* smWg = smW + ((size_t)(b * G_ + g) * TPP_) * D_;
    const int h = lane >> 4;

    float rs[4][4];
#pragma unroll
    for (int mi = 0; mi < 4; ++mi)
#pragma unroll
        for (int e = 0; e < 4; ++e) rs[mi][e] = 0.f;

#pragma unroll
    for (int ni = 0; ni < 4; ++ni) {
        int col = tn * 256 + wn * 64 + ni * 16 + (lane & 15);
        float ccv = cc[b * D_ + col];
        float w2v = W2[col];
#pragma unroll
        for (int mi = 0; mi < 4; ++mi)
#pragma unroll
            for (int e = 0; e < 4; ++e) {
                int trow = mi * 16 + h * 4 + e;
                float v = acc[mi][ni][e] + ccv +
                          bfu2f(*reinterpret_cast<const unsigned short*>(
                              &smWg[(size_t)trow * D_ + col]));
                rs[mi][e] += fmaxf(v, 0.f) * w2v;
            }
    }
#pragma unroll
    for (int off = 8; off >= 1; off >>= 1)
#pragma unroll
        for (int mi = 0; mi < 4; ++mi)
#pragma unroll
            for (int e = 0; e < 4; ++e) rs[mi][e] += __shfl_xor(rs[mi][e], off);

    if ((lane & 15) == 0) {
#pragma unroll
        for (int mi = 0; mi < 4; ++mi)
#pragma unroll
            for (int e = 0; e < 4; ++e)
                rowsum[wn][wm * 64 + mi * 16 + h * 4 + e] = rs[mi][e];
    }
    __syncthreads();

    if (tid < 128) {
        int pp = tid >> 6, t = tid & 63;
        float v = (rowsum[0][tid] + rowsum[1][tid] + rowsum[2][tid] +
                   rowsum[3][tid]) *
                  mask[((size_t)b * P_ + tm * 2 + pp) * TPP_ + t];
#pragma unroll
        for (int off = 32; off >= 1; off >>= 1) v += __shfl_xor(v, off);
        if (t == 0) atomicAdd(&out[b * P_ + tm * 2 + pp], v);
    }
}

// ---------------------------------------------------------------------------
extern "C" void kernel_launch(void* const* d_in, const int* in_sizes, int n_in,
                              void* d_out, int out_size, void* d_ws, size_t ws_size,
                              hipStream_t stream)
{
    const float* answer = (const float*)d_in[0];
    const float* qps    = (const float*)d_in[1];
    const float* mask   = (const float*)d_in[2];
    const int*   tids   = (const int*)d_in[3];
    // d_in[4] = fusion_scores: unused by the reference
    const float* W_p = (const float*)d_in[5];
    const float* b_p = (const float*)d_in[6];
    const float* W_t = (const float*)d_in[7];
    const float* b_t = (const float*)d_in[8];
    const float* W1  = (const float*)d_in[9];
    const float* b1  = (const float*)d_in[10];
    const float* W2  = (const float*)d_in[11];
    const float* b2  = (const float*)d_in[12];
    float* out = (float*)d_out;

    char* ws = (char*)d_ws;
    __hip_bfloat16* Wpe_nat = (__hip_bfloat16*)ws; ws += (size_t)B_ * D_ * D_ * 2;
    __hip_bfloat16* Wbig    = (__hip_bfloat16*)ws; ws += (size_t)B_ * NC_ * D_ * 2;
    float* c_p = (float*)ws;                   ws += (size_t)B_ * D_ * 4;
    float* c_t = (float*)ws;                   ws += (size_t)B_ * D_ * 4;
    float* cc  = (float*)ws;                   ws += (size_t)B_ * D_ * 4;
    __hip_bfloat16* qb = (__hip_bfloat16*)ws;  ws += (size_t)B_ * T_ * D_ * 2;
    __hip_bfloat16* ts = (__hip_bfloat16*)ws;  ws += (size_t)B_ * T_ * D_ * 2;
    __hip_bfloat16* sm = (__hip_bfloat16*)ws;  ws += (size_t)B_ * G_ * TPP_ * D_ * 2;
    __hip_bfloat16* smW = (__hip_bfloat16*)ws; ws += (size_t)B_ * G_ * TPP_ * D_ * 2;
    __hip_bfloat16* W1at = (__hip_bfloat16*)ws; ws += (size_t)D_ * D_ * 2;
    __hip_bfloat16* W1bt = (__hip_bfloat16*)ws; ws += (size_t)D_ * D_ * 2;
    int* glist = (int*)ws;                     ws += B_ * P_ * 4;
    int* goff  = (int*)ws;                     ws += B_ * (G_ + 1) * 4;

    prep_all<<<11091, 256, 0, stream>>>(
        answer, W_p, b_p, W_t, b_t, W1, qps, tids, mask, b2,
        Wpe_nat, Wbig, c_p, c_t, qb, W1at, W1bt, glist, goff, out);
    fused_ts_c1<<<720, 512, 0, stream>>>(
        qb, Wbig, c_t, ts, W1at, Wpe_nat, c_p, W1, b1, cc);
    segmax_kernel<<<(B_ * TPP_ * (D_ / 4)) / 256, 256, 0, stream>>>(
        ts, glist, goff, sm);
    gemm_smw<<<60, 512, 0, stream>>>(sm, W1bt, smW);
    gemm_fin<<<600, 512, 0, stream>>>(
        qb, Wbig, cc, smW, tids, W2, mask, out);
}

// Round 14
// 202.451 us; speedup vs baseline: 1.0426x; 1.0426x over previous
//
#include <hip/hip_runtime.h>
#include <hip/hip_bf16.h>

#define B_ 4
#define L_ 2
#define P_ 100
#define TPP_ 64
#define D_ 768
#define G_ 10
#define T_ (P_ * TPP_)   // 6400
#define NC_ (2 * D_)     // 1536

typedef __attribute__((ext_vector_type(8))) short bf16x8;
typedef __attribute__((ext_vector_type(4))) float f32x4;

__device__ __forceinline__ unsigned short f2bf(float f) {
    __hip_bfloat16 h = __float2bfloat16(f);
    return *reinterpret_cast<unsigned short*>(&h);
}
__device__ __forceinline__ float bfu2f(unsigned short u) {
    return __uint_as_float(((unsigned int)u) << 16);
}

__device__ __forceinline__ void gload_lds16(const void* g, void* l) {
    __builtin_amdgcn_global_load_lds(
        (const __attribute__((address_space(1))) void*)g,
        (__attribute__((address_space(3))) void*)l, 16, 0, 0);
}

#define SBAR()   __builtin_amdgcn_s_barrier()
#define SCHEDB() __builtin_amdgcn_sched_barrier(0)
#define VMCNT8() asm volatile("s_waitcnt vmcnt(8)" ::: "memory")
#define VMCNT4() asm volatile("s_waitcnt vmcnt(4)" ::: "memory")
#define VMCNT0() asm volatile("s_waitcnt vmcnt(0)" ::: "memory")

// ---------------------------------------------------------------------------
// BK=32, 128x128 tile, 4 waves.  3 named buffers (48 KB LDS -> 3 blocks/CU)
// give a depth-2 prefetch: stage(t+3) issues after compute(t), so each tile's
// loads get ~2 compute phases of latency cover (vs 1 in the r12 2-buffer loop).
// Both-sides swizzle for 64B rows:  LDS[r][s] = G[r][s ^ ((r>>1)&3)]
//   write: linear gload_lds dest + pre-swizzled per-lane GLOBAL source
//   read:  slot = h ^ ((rr>>1)&3)
// Bank check (ds_read_b128): rows 0-7 hit 8 distinct 4-bank groups, 2-way
// aliasing overall (free, m136) — same structure as the validated BK=64 path.
// 4 loads/thread/tile -> steady-state vmcnt(8) (2 tiles in flight).
// ---------------------------------------------------------------------------
__device__ __forceinline__ void stage32(
    const __hip_bfloat16* __restrict__ Ag, const __hip_bfloat16* __restrict__ Bg,
    int k0, __hip_bfloat16 (*As)[32], __hip_bfloat16 (*Bs)[32],
    int w, int row16, int soff)
{
#pragma unroll
    for (int j = 0; j < 2; ++j) {
        int r = w * 32 + j * 16 + row16;   // wave covers 32 A-rows + 32 B-rows
        gload_lds16(Ag + (size_t)r * D_ + k0 + soff, &As[w * 32 + j * 16][0]);
        gload_lds16(Bg + (size_t)r * D_ + k0 + soff, &Bs[w * 32 + j * 16][0]);
    }
}

__device__ __forceinline__ void mfma_step32(
    __hip_bfloat16 (*As)[32], __hip_bfloat16 (*Bs)[32],
    int rr, int rsl, int wm, int wn, f32x4 acc[4][4])
{
    bf16x8 af[4], bfr[4];
#pragma unroll
    for (int mi = 0; mi < 4; ++mi)
        af[mi] = *reinterpret_cast<const bf16x8*>(
            &As[wm * 64 + mi * 16 + rr][rsl]);
#pragma unroll
    for (int ni = 0; ni < 4; ++ni)
        bfr[ni] = *reinterpret_cast<const bf16x8*>(
            &Bs[wn * 64 + ni * 16 + rr][rsl]);
#pragma unroll
    for (int mi = 0; mi < 4; ++mi)
#pragma unroll
        for (int ni = 0; ni < 4; ++ni)
            acc[mi][ni] = __builtin_amdgcn_mfma_f32_16x16x32_bf16(
                af[mi], bfr[ni], acc[mi][ni], 0, 0, 0);
}

#define MFMA_STEP_P(As, Bs)                                                   \
    __builtin_amdgcn_s_setprio(1);                                            \
    mfma_step32(As, Bs, rr, rsl, wm, wn, acc);                                \
    __builtin_amdgcn_s_setprio(0);

// 24 K-tiles; 7 macro-iters of 3 cover t=0..20 (staging through tile 23),
// then a 3-step epilogue with vmcnt 8 -> 4 -> 0.
#define MFMA_LOOP_PIPE(Ag, Bg)                                                \
    {                                                                         \
        const int rr = lane & 15, h = lane >> 4;                              \
        const int row16 = lane >> 2;                                          \
        const int soff = ((lane & 3) ^ ((lane >> 3) & 3)) << 3;               \
        const int rsl = (h ^ ((rr >> 1) & 3)) << 3;                           \
        stage32((Ag), (Bg), 0,  As0, Bs0, w, row16, soff);                    \
        stage32((Ag), (Bg), 32, As1, Bs1, w, row16, soff);                    \
        stage32((Ag), (Bg), 64, As2, Bs2, w, row16, soff);                    \
        SCHEDB();                                                             \
        for (int t = 0; t < 21; t += 3) {                                     \
            VMCNT8(); SBAR(); SCHEDB();                                       \
            MFMA_STEP_P(As0, Bs0);                                            \
            SCHEDB(); SBAR(); SCHEDB();                                       \
            stage32((Ag), (Bg), (t + 3) * 32, As0, Bs0, w, row16, soff);      \
            SCHEDB();                                                         \
            VMCNT8(); SBAR(); SCHEDB();                                       \
            MFMA_STEP_P(As1, Bs1);                                            \
            SCHEDB(); SBAR(); SCHEDB();                                       \
            stage32((Ag), (Bg), (t + 4) * 32, As1, Bs1, w, row16, soff);      \
            SCHEDB();                                                         \
            VMCNT8(); SBAR(); SCHEDB();                                       \
            MFMA_STEP_P(As2, Bs2);                                            \
            SCHEDB(); SBAR(); SCHEDB();                                       \
            stage32((Ag), (Bg), (t + 5) * 32, As2, Bs2, w, row16, soff);      \
            SCHEDB();                                                         \
        }                                                                     \
        VMCNT8(); SBAR(); SCHEDB();                                           \
        MFMA_STEP_P(As0, Bs0);                        /* tile 21 */           \
        SCHEDB();                                                             \
        VMCNT4(); SBAR(); SCHEDB();                                           \
        MFMA_STEP_P(As1, Bs1);                        /* tile 22 */           \
        SCHEDB();                                                             \
        VMCNT0(); SBAR(); SCHEDB();                                           \
        MFMA_STEP_P(As2, Bs2);                        /* tile 23 */           \
        __syncthreads();                                                      \
    }

#define DECL_LDS_DB()                                                         \
    __shared__ __align__(16) __hip_bfloat16 As0[128][32];  /* 8 KB */         \
    __shared__ __align__(16) __hip_bfloat16 Bs0[128][32];                     \
    __shared__ __align__(16) __hip_bfloat16 As1[128][32];                     \
    __shared__ __align__(16) __hip_bfloat16 Bs1[128][32];                     \
    __shared__ __align__(16) __hip_bfloat16 As2[128][32];                     \
    __shared__ __align__(16) __hip_bfloat16 Bs2[128][32];  /* 48 KB total */

#define DECL_ACC()                                                            \
    f32x4 acc[4][4];                                                          \
    _Pragma("unroll") for (int i = 0; i < 4; ++i)                             \
        _Pragma("unroll") for (int j = 0; j < 4; ++j)                         \
            _Pragma("unroll") for (int e = 0; e < 4; ++e) acc[i][j][e] = 0.0f;

// ---------------------------------------------------------------------------
// P-ALL (validated r9/r12): wct / const / w1t / groups / out_init / conv_q.
// ---------------------------------------------------------------------------
__global__ __launch_bounds__(256) void prep_all(
    const float* __restrict__ answer, const float* __restrict__ W_p,
    const float* __restrict__ b_p, const float* __restrict__ W_t,
    const float* __restrict__ b_t, const float* __restrict__ W1,
    const float* __restrict__ qps, const int* __restrict__ tids,
    const float* __restrict__ mask, const float* __restrict__ b2,
    __hip_bfloat16* __restrict__ Wpe_nat, __hip_bfloat16* __restrict__ Wbig,
    float* __restrict__ c_p, float* __restrict__ c_t,
    __hip_bfloat16* __restrict__ qb, __hip_bfloat16* __restrict__ W1at,
    __hip_bfloat16* __restrict__ W1bt, int* __restrict__ glist,
    int* __restrict__ goff, float* __restrict__ out)
{
    __shared__ float lds[64][65];
    __shared__ float a_s[64];
    __shared__ float red2[2][4][64];
    __shared__ int g_cnt[B_][G_];
    __shared__ int g_off[B_][G_ + 1];
    __shared__ int g_cur[B_][G_];

    const int bid = blockIdx.x;
    const int tid = threadIdx.x;

    if (bid < 1152) {
        const int n0 = (bid % 24) * 64;
        const int k0 = ((bid / 24) % 12) * 64;
        const int b  = bid / 288;
        if (tid < 64) a_s[tid] = answer[((size_t)b * L_ + (L_ - 1)) * D_ + k0 + tid];
        __syncthreads();
        if (n0 < D_) {
#pragma unroll
            for (int i = 0; i < 16; ++i) {
                int k = (tid >> 6) + i * 4;
                int n = tid & 63;
                float v = W_p[(size_t)(D_ + k0 + k) * D_ + n0 + n] +
                          a_s[k] * W_p[(size_t)(2 * D_ + k0 + k) * D_ + n0 + n];
                Wpe_nat[(size_t)b * D_ * D_ + (size_t)(k0 + k) * D_ + n0 + n] =
                    __float2bfloat16(v);
            }
        } else {
            const int nn0 = n0 - D_;
#pragma unroll
            for (int i = 0; i < 16; ++i) {
                int k = (tid >> 6) + i * 4;
                int n = tid & 63;
                lds[k][n] = W_t[(size_t)(D_ + k0 + k) * D_ + nn0 + n] +
                            a_s[k] * W_t[(size_t)(2 * D_ + k0 + k) * D_ + nn0 + n];
            }
            __syncthreads();
#pragma unroll
            for (int j = 0; j < 16; ++j) {
                int n = (tid >> 6) + j * 4;
                int kk = tid & 63;
                Wbig[((size_t)b * NC_ + n0 + n) * D_ + k0 + kk] =
                    __float2bfloat16(lds[kk][n]);
            }
        }
    } else if (bid < 1200) {
        const int local = bid - 1152;
        const int b = local / 12;
        const int d = (local % 12) * 64 + (tid & 63);
        const int ks = tid >> 6;
        const float* a = answer + ((size_t)b * L_ + (L_ - 1)) * D_;
        float sp = 0.f, st = 0.f;
#pragma unroll 4
        for (int k = ks; k < D_; k += 4) {
            float av = a[k];
            sp += av * W_p[(size_t)k * D_ + d];
            st += av * W_t[(size_t)k * D_ + d];
        }
        red2[0][ks][tid & 63] = sp;
        red2[1][ks][tid & 63] = st;
        __syncthreads();
        if (ks == 0) {
            float s1 = b_p[d], s2 = b_t[d];
#pragma unroll
            for (int i = 0; i < 4; ++i) {
                s1 += red2[0][i][tid & 63];
                s2 += red2[1][i][tid & 63];
            }
            c_p[b * D_ + d] = s1;
            c_t[b * D_ + d] = s2;
        }
    } else if (bid < 1488) {
        const int local = bid - 1200;
        const int n0 = (local % 12) * 64;
        const int k0 = (local / 12) * 64;
#pragma unroll
        for (int i = 0; i < 16; ++i) {
            int k = (tid >> 6) + i * 4;
            int n = tid & 63;
            lds[k][n] = W1[(size_t)(k0 + k) * D_ + n0 + n];
        }
        __syncthreads();
        __hip_bfloat16* dst = (k0 < D_) ? W1at : W1bt;
        const int kk0 = (k0 < D_) ? k0 : k0 - D_;
#pragma unroll
        for (int j = 0; j < 16; ++j) {
            int n = (tid >> 6) + j * 4;
            int kk = tid & 63;
            dst[(size_t)(n0 + n) * D_ + kk0 + kk] = __float2bfloat16(lds[kk][n]);
        }
    } else if (bid == 1488) {
        if (tid < B_ * G_) g_cnt[tid / G_][tid % G_] = 0;
        __syncthreads();
        for (int i = tid; i < B_ * P_; i += 256)
            atomicAdd(&g_cnt[i / P_][tids[i]], 1);
        __syncthreads();
        if (tid < B_) {
            int o = 0;
            for (int g = 0; g < G_; ++g) { g_off[tid][g] = o; o += g_cnt[tid][g]; }
            g_off[tid][G_] = o;
            for (int g = 0; g <= G_; ++g) goff[tid * (G_ + 1) + g] = g_off[tid][g];
        }
        __syncthreads();
        if (tid < B_ * G_) g_cur[tid / G_][tid % G_] = g_off[tid / G_][tid % G_];
        __syncthreads();
        for (int i = tid; i < B_ * P_; i += 256) {
            int b = i / P_, p = i % P_;
            int slot = atomicAdd(&g_cur[b][tids[i]], 1);
            glist[b * P_ + slot] = p;
        }
    } else if (bid < 1491) {
        int bp = (bid - 1489) * 256 + tid;
        if (bp < B_ * P_) {
            float s = 0.f;
#pragma unroll 8
            for (int t = 0; t < TPP_; ++t) s += mask[(size_t)bp * TPP_ + t];
            out[bp] = s * b2[0];
        }
    } else {
        size_t base = ((size_t)(bid - 1491) * 256 + tid) * 8;
        int b = (int)(base / ((size_t)T_ * D_));
        size_t off = base % ((size_t)T_ * D_);
        const float4* src = reinterpret_cast<const float4*>(
            qps + ((size_t)b * L_ + (L_ - 1)) * (size_t)T_ * D_ + off);
        float4 v0 = src[0], v1 = src[1];
        bf16x8 o;
        o[0] = (short)f2bf(v0.x); o[1] = (short)f2bf(v0.y);
        o[2] = (short)f2bf(v0.z); o[3] = (short)f2bf(v0.w);
        o[4] = (short)f2bf(v1.x); o[5] = (short)f2bf(v1.y);
        o[6] = (short)f2bf(v1.z); o[7] = (short)f2bf(v1.w);
        *reinterpret_cast<bf16x8*>(&qb[base]) = o;
    }
}

// ---------------------------------------------------------------------------
// FUSED K2 (r12 geometry): [0,1200) ts (XCD-swizzled); [1200,1344) gemm_c1;
// [1344,1392) prep_cc.
// ---------------------------------------------------------------------------
__global__ __launch_bounds__(256) void fused_ts_c1(
    const __hip_bfloat16* __restrict__ qb, __hip_bfloat16* __restrict__ Wbig,
    const float* __restrict__ c_t, __hip_bfloat16* __restrict__ ts,
    const __hip_bfloat16* __restrict__ W1at,
    const __hip_bfloat16* __restrict__ Wpe_nat,
    const float* __restrict__ c_p, const float* __restrict__ W1,
    const float* __restrict__ b1, float* __restrict__ cc)
{
    DECL_LDS_DB();
    __shared__ float red[4][64];
    const int bid = blockIdx.x;
    const int tid = threadIdx.x;
    const int lane = tid & 63, w = tid >> 6;
    const int wm = w & 1, wn = w >> 1;

    if (bid < 1200) {
        const int swz = (bid & 7) * 150 + (bid >> 3);
        const int tn = swz % 6;
        const int tmb = swz / 6;
        const int tm = tmb % 50, b = tmb / 50;
        DECL_ACC();
        const __hip_bfloat16* Ag = qb + (size_t)b * T_ * D_ + (size_t)tm * 128 * D_;
        const __hip_bfloat16* Bg =
            Wbig + (size_t)b * NC_ * D_ + (size_t)(D_ + tn * 128) * D_;
        MFMA_LOOP_PIPE(Ag, Bg);
#pragma unroll
        for (int mi = 0; mi < 4; ++mi)
#pragma unroll
            for (int ni = 0; ni < 4; ++ni) {
                int col = tn * 128 + wn * 64 + ni * 16 + (lane & 15);
                int rb  = tm * 128 + wm * 64 + mi * 16 + (lane >> 4) * 4;
                float cv = c_t[b * D_ + col];
#pragma unroll
                for (int e = 0; e < 4; ++e)
                    ts[((size_t)b * T_ + rb + e) * D_ + col] =
                        __float2bfloat16(acc[mi][ni][e] + cv);
            }
    } else if (bid < 1344) {
        const int local = bid - 1200;
        const int tm = local % 6, tn = (local / 6) % 6, b = local / 36;
        DECL_ACC();
        const __hip_bfloat16* Ag = W1at + (size_t)tm * 128 * D_;
        const __hip_bfloat16* Bg =
            Wpe_nat + (size_t)b * D_ * D_ + (size_t)tn * 128 * D_;
        MFMA_LOOP_PIPE(Ag, Bg);
#pragma unroll
        for (int mi = 0; mi < 4; ++mi)
#pragma unroll
            for (int ni = 0; ni < 4; ++ni) {
                int col = tn * 128 + wn * 64 + ni * 16 + (lane & 15);
                int row = tm * 128 + wm * 64 + mi * 16 + (lane >> 4) * 4;
#pragma unroll
                for (int e = 0; e < 4; ++e)
                    Wbig[(size_t)b * NC_ * D_ + (size_t)(row + e) * D_ + col] =
                        __float2bfloat16(acc[mi][ni][e]);
            }
    } else {
        const int local = bid - 1344;
        const int b = local / 12;
        const int n = (local % 12) * 64 + (tid & 63);
        const int ks = tid >> 6;
        float s = 0.f;
#pragma unroll 4
        for (int d = ks; d < D_; d += 4)
            s += c_p[b * D_ + d] * W1[(size_t)d * D_ + n];
        red[ks][tid & 63] = s;
        __syncthreads();
        if (ks == 0) {
            float tot = b1[n];
#pragma unroll
            for (int i = 0; i < 4; ++i) tot += red[i][tid & 63];
            cc[b * D_ + n] = tot;
        }
    }
}

// ---------------------------------------------------------------------------
// K3: segment max via group lists; 4 d's per thread
// ---------------------------------------------------------------------------
__global__ __launch_bounds__(256) void segmax_kernel(
    const __hip_bfloat16* __restrict__ ts, const int* __restrict__ glist,
    const int* __restrict__ goff, __hip_bfloat16* __restrict__ sm)
{
    int idx = blockIdx.x * 256 + threadIdx.x;
    int d4 = idx % (D_ / 4);
    int bt = idx / (D_ / 4);
    int t = bt % TPP_;
    int b = bt / TPP_;

    const ushort4* base =
        reinterpret_cast<const ushort4*>(ts + ((size_t)b * T_ + t) * D_) + d4;

    for (int g = 0; g < G_; ++g) {
        float m0 = -1e30f, m1 = -1e30f, m2 = -1e30f, m3 = -1e30f;
        int i0 = goff[b * (G_ + 1) + g], i1 = goff[b * (G_ + 1) + g + 1];
        for (int i = i0; i < i1; ++i) {
            int p = glist[b * P_ + i];
            ushort4 u = base[(size_t)p * TPP_ * (D_ / 4)];
            m0 = fmaxf(m0, bfu2f(u.x));
            m1 = fmaxf(m1, bfu2f(u.y));
            m2 = fmaxf(m2, bfu2f(u.z));
            m3 = fmaxf(m3, bfu2f(u.w));
        }
        ushort4 o;
        o.x = f2bf(m0); o.y = f2bf(m1); o.z = f2bf(m2); o.w = f2bf(m3);
        reinterpret_cast<ushort4*>(
            sm + (((size_t)b * G_ + g) * TPP_ + t) * D_)[d4] = o;
    }
}

// ---------------------------------------------------------------------------
// K4: smW = sm @ W1bt^T  (120 blocks, XCD-swizzled: 120 = 8*15)
// ---------------------------------------------------------------------------
__global__ __launch_bounds__(256) void gemm_smw(
    const __hip_bfloat16* __restrict__ sm, const __hip_bfloat16* __restrict__ W1bt,
    __hip_bfloat16* __restrict__ smW)
{
    const int swz = (blockIdx.x & 7) * 15 + (blockIdx.x >> 3);
    const int tn = swz % 6, tm = swz / 6;
    DECL_LDS_DB();
    const int tid = threadIdx.x;
    const int lane = tid & 63, w = tid >> 6;
    const int wm = w & 1, wn = w >> 1;
    DECL_ACC();

    const __hip_bfloat16* Ag = sm + (size_t)tm * 128 * D_;
    const __hip_bfloat16* Bg = W1bt + (size_t)tn * 128 * D_;
    MFMA_LOOP_PIPE(Ag, Bg);

#pragma unroll
    for (int mi = 0; mi < 4; ++mi)
#pragma unroll
        for (int ni = 0; ni < 4; ++ni) {
            int col = tn * 128 + wn * 64 + ni * 16 + (lane & 15);
            int rb  = tm * 128 + wm * 64 + mi * 16 + (lane >> 4) * 4;
#pragma unroll
            for (int e = 0; e < 4; ++e)
                smW[(size_t)(rb + e) * D_ + col] = __float2bfloat16(acc[mi][ni][e]);
        }
}

// ---------------------------------------------------------------------------
// K5: fused  acc = qb @ Wbig[b][0..768]^T ; v = relu(acc + cc + smW[g])
//     rowdot = v . W2 ; out[b][p] += sum_t mask * rowdot
//     1200 blocks 1D, XCD-swizzled (r12 geometry).
// ---------------------------------------------------------------------------
__global__ __launch_bounds__(256) void gemm_fin(
    const __hip_bfloat16* __restrict__ qb, const __hip_bfloat16* __restrict__ Wbig,
    const float* __restrict__ cc, const __hip_bfloat16* __restrict__ smW,
    const int* __restrict__ tids, const float* __restrict__ W2,
    const float* __restrict__ mask, float* __restrict__ out)
{
    const int swz = (blockIdx.x & 7) * 150 + (blockIdx.x >> 3);
    const int tn = swz % 6;
    const int tmb = swz / 6;
    const int tm = tmb % 50, b = tmb / 50;
    DECL_LDS_DB();
    __shared__ float rowsum[2][128];

    const int tid = threadIdx.x;
    const int lane = tid & 63, w = tid >> 6;
    const int wm = w & 1, wn = w >> 1;
    DECL_ACC();

    const __hip_bfloat16* Ag = qb + (size_t)b * T_ * D_ + (size_t)tm * 128 * D_;
    const __hip_bfloat16* Bg = Wbig + (size_t)b * NC_ * D_ + (size_t)tn * 128 * D_;
    MFMA_LOOP_PIPE(Ag, Bg);

    const int p = tm * 2 + wm;
    const int g = tids[b * P_ + p];
    const __hip_bfloat16* smWg = smW + ((size_t)(b * G_ + g) * TPP_) * D_;
    const int h = lane >> 4;

    float rs[4][4];
#pragma unroll
    for (int mi = 0; mi < 4; ++mi)
#pragma unroll
        for (int e = 0; e < 4; ++e) rs[mi][e] = 0.f;

#pragma unroll
    for (int ni = 0; ni < 4; ++ni) {
        int col = tn * 128 + wn * 64 + ni * 16 + (lane & 15);
        float ccv = cc[b * D_ + col];
        float w2v = W2[col];
#pragma unroll
        for (int mi = 0; mi < 4; ++mi)
#pragma unroll
            for (int e = 0; e < 4; ++e) {
                int trow = mi * 16 + h * 4 + e;
                float v = acc[mi][ni][e] + ccv +
                          bfu2f(*reinterpret_cast<const unsigned short*>(
                              &smWg[(size_t)trow * D_ + col]));
                rs[mi][e] += fmaxf(v, 0.f) * w2v;
            }
    }
#pragma unroll
    for (int off = 8; off >= 1; off >>= 1)
#pragma unroll
        for (int mi = 0; mi < 4; ++mi)
#pragma unroll
            for (int e = 0; e < 4; ++e) rs[mi][e] += __shfl_xor(rs[mi][e], off);

    if ((lane & 15) == 0) {
#pragma unroll
        for (int mi = 0; mi < 4; ++mi)
#pragma unroll
            for (int e = 0; e < 4; ++e)
                rowsum[wn][wm * 64 + mi * 16 + h * 4 + e] = rs[mi][e];
    }
    __syncthreads();

    if (tid < 128) {
        int pp = tid >> 6, t = tid & 63;
        float v = (rowsum[0][tid] + rowsum[1][tid]) *
                  mask[((size_t)b * P_ + tm * 2 + pp) * TPP_ + t];
#pragma unroll
        for (int off = 32; off >= 1; off >>= 1) v += __shfl_xor(v, off);
        if (t == 0) atomicAdd(&out[b * P_ + tm * 2 + pp], v);
    }
}

// ---------------------------------------------------------------------------
extern "C" void kernel_launch(void* const* d_in, const int* in_sizes, int n_in,
                              void* d_out, int out_size, void* d_ws, size_t ws_size,
                              hipStream_t stream)
{
    const float* answer = (const float*)d_in[0];
    const float* qps    = (const float*)d_in[1];
    const float* mask   = (const float*)d_in[2];
    const int*   tids   = (const int*)d_in[3];
    // d_in[4] = fusion_scores: unused by the reference
    const float* W_p = (const float*)d_in[5];
    const float* b_p = (const float*)d_in[6];
    const float* W_t = (const float*)d_in[7];
    const float* b_t = (const float*)d_in[8];
    const float* W1  = (const float*)d_in[9];
    const float* b1  = (const float*)d_in[10];
    const float* W2  = (const float*)d_in[11];
    const float* b2  = (const float*)d_in[12];
    float* out = (float*)d_out;

    char* ws = (char*)d_ws;
    __hip_bfloat16* Wpe_nat = (__hip_bfloat16*)ws; ws += (size_t)B_ * D_ * D_ * 2;
    __hip_bfloat16* Wbig    = (__hip_bfloat16*)ws; ws += (size_t)B_ * NC_ * D_ * 2;
    float* c_p = (float*)ws;                   ws += (size_t)B_ * D_ * 4;
    float* c_t = (float*)ws;                   ws += (size_t)B_ * D_ * 4;
    float* cc  = (float*)ws;                   ws += (size_t)B_ * D_ * 4;
    __hip_bfloat16* qb = (__hip_bfloat16*)ws;  ws += (size_t)B_ * T_ * D_ * 2;
    __hip_bfloat16* ts = (__hip_bfloat16*)ws;  ws += (size_t)B_ * T_ * D_ * 2;
    __hip_bfloat16* sm = (__hip_bfloat16*)ws;  ws += (size_t)B_ * G_ * TPP_ * D_ * 2;
    __hip_bfloat16* smW = (__hip_bfloat16*)ws; ws += (size_t)B_ * G_ * TPP_ * D_ * 2;
    __hip_bfloat16* W1at = (__hip_bfloat16*)ws; ws += (size_t)D_ * D_ * 2;
    __hip_bfloat16* W1bt = (__hip_bfloat16*)ws; ws += (size_t)D_ * D_ * 2;
    int* glist = (int*)ws;                     ws += B_ * P_ * 4;
    int* goff  = (int*)ws;                     ws += B_ * (G_ + 1) * 4;

    prep_all<<<11091, 256, 0, stream>>>(
        answer, W_p, b_p, W_t, b_t, W1, qps, tids, mask, b2,
        Wpe_nat, Wbig, c_p, c_t, qb, W1at, W1bt, glist, goff, out);
    fused_ts_c1<<<1392, 256, 0, stream>>>(
        qb, Wbig, c_t, ts, W1at, Wpe_nat, c_p, W1, b1, cc);
    segmax_kernel<<<(B_ * TPP_ * (D_ / 4)) / 256, 256, 0, stream>>>(
        ts, glist, goff, sm);
    gemm_smw<<<120, 256, 0, stream>>>(sm, W1bt, smW);
    gemm_fin<<<1200, 256, 0, stream>>>(
        qb, Wbig, cc, smW, tids, W2, mask, out);
}

// Round 15
// 174.838 us; speedup vs baseline: 1.2072x; 1.1579x over previous
//
#include <hip/hip_runtime.h>
#include <hip/hip_bf16.h>

#define B_ 4
#define L_ 2
#define P_ 100
#define TPP_ 64
#define D_ 768
#define G_ 10
#define T_ (P_ * TPP_)   // 6400
#define NC_ (2 * D_)     // 1536

typedef __attribute__((ext_vector_type(8))) short bf16x8;
typedef __attribute__((ext_vector_type(4))) float f32x4;

__device__ __forceinline__ unsigned short f2bf(float f) {
    __hip_bfloat16 h = __float2bfloat16(f);
    return *reinterpret_cast<unsigned short*>(&h);
}
__device__ __forceinline__ float bfu2f(unsigned short u) {
    return __uint_as_float(((unsigned int)u) << 16);
}

__device__ __forceinline__ void gload_lds16(const void* g, void* l) {
    __builtin_amdgcn_global_load_lds(
        (const __attribute__((address_space(1))) void*)g,
        (__attribute__((address_space(3))) void*)l, 16, 0, 0);
}

#define SBAR()   __builtin_amdgcn_s_barrier()
#define SCHEDB() __builtin_amdgcn_sched_barrier(0)
#define VMCNT8() asm volatile("s_waitcnt vmcnt(8)" ::: "memory")
#define VMCNT0() asm volatile("s_waitcnt vmcnt(0)" ::: "memory")

// Monotonic float<->uint order-preserving transform for atomicMax-based
// segment max:  key = bits ^ ((bits>>31) | 0x80000000).  max over keys ==
// max over floats; bf16-rounding is monotone so rounding after the max
// equals the reference's max-after-rounding.
__device__ __forceinline__ unsigned int fenc(float v) {
    unsigned int bits = __float_as_uint(v);
    return bits ^ (unsigned int)(((int)bits >> 31) | 0x80000000);
}
__device__ __forceinline__ float fdec(unsigned int k) {
    unsigned int bits = (k & 0x80000000u) ? (k ^ 0x80000000u) : ~k;
    return __uint_as_float(bits);
}

// ---------------------------------------------------------------------------
// BK=64 stage + both-sides 8x16B-slot swizzle (validated r6-r12, r12 loop
// verbatim: 2 named buffers, counted vmcnt(8), setprio). 8 loads/thread/tile.
// ---------------------------------------------------------------------------
__device__ __forceinline__ void stage64(
    const __hip_bfloat16* __restrict__ Ag, const __hip_bfloat16* __restrict__ Bg,
    int k0, __hip_bfloat16 (*As)[64], __hip_bfloat16 (*Bs)[64],
    int w, int row_l, int soff)
{
#pragma unroll
    for (int j = 0; j < 4; ++j) {
        int r = w * 32 + j * 8 + row_l;   // r&7 == row_l
        gload_lds16(Ag + (size_t)r * D_ + k0 + soff, &As[w * 32 + j * 8][0]);
        gload_lds16(Bg + (size_t)r * D_ + k0 + soff, &Bs[w * 32 + j * 8][0]);
    }
}

__device__ __forceinline__ void mfma_step64(
    __hip_bfloat16 (*As)[64], __hip_bfloat16 (*Bs)[64],
    int rr, int h, int wm, int wn, f32x4 acc[4][4])
{
#pragma unroll
    for (int ks = 0; ks < 2; ++ks) {
        const int rsl = (((ks << 2) + h) ^ (rr & 7)) << 3;
        bf16x8 af[4], bfr[4];
#pragma unroll
        for (int mi = 0; mi < 4; ++mi)
            af[mi] = *reinterpret_cast<const bf16x8*>(
                &As[wm * 64 + mi * 16 + rr][rsl]);
#pragma unroll
        for (int ni = 0; ni < 4; ++ni)
            bfr[ni] = *reinterpret_cast<const bf16x8*>(
                &Bs[wn * 64 + ni * 16 + rr][rsl]);
#pragma unroll
        for (int mi = 0; mi < 4; ++mi)
#pragma unroll
            for (int ni = 0; ni < 4; ++ni)
                acc[mi][ni] = __builtin_amdgcn_mfma_f32_16x16x32_bf16(
                    af[mi], bfr[ni], acc[mi][ni], 0, 0, 0);
    }
}

#define MFMA_STEP_P(As, Bs)                                                   \
    __builtin_amdgcn_s_setprio(1);                                            \
    mfma_step64(As, Bs, rr, h, wm, wn, acc);                                  \
    __builtin_amdgcn_s_setprio(0);

// T4 counted-vmcnt pipeline (r12 verbatim).
#define MFMA_LOOP_PIPE(Ag, Bg)                                                \
    {                                                                         \
        const int rr = lane & 15, h = lane >> 4;                              \
        const int row_l = lane >> 3;                                          \
        const int soff = ((lane & 7) ^ row_l) << 3;                           \
        stage64((Ag), (Bg), 0, As0, Bs0, w, row_l, soff);                     \
        stage64((Ag), (Bg), 64, As1, Bs1, w, row_l, soff);                    \
        SCHEDB();                                                             \
        for (int t = 0; t < 10; t += 2) {                                     \
            VMCNT8(); SBAR(); SCHEDB();                                       \
            MFMA_STEP_P(As0, Bs0);                                            \
            SCHEDB(); SBAR(); SCHEDB();                                       \
            stage64((Ag), (Bg), (t + 2) * 64, As0, Bs0, w, row_l, soff);      \
            SCHEDB();                                                         \
            VMCNT8(); SBAR(); SCHEDB();                                       \
            MFMA_STEP_P(As1, Bs1);                                            \
            SCHEDB(); SBAR(); SCHEDB();                                       \
            stage64((Ag), (Bg), (t + 3) * 64, As1, Bs1, w, row_l, soff);      \
            SCHEDB();                                                         \
        }                                                                     \
        VMCNT8(); SBAR(); SCHEDB();                                           \
        MFMA_STEP_P(As0, Bs0);                        /* tile 10 */           \
        SCHEDB();                                                             \
        VMCNT0(); SBAR(); SCHEDB();                                           \
        MFMA_STEP_P(As1, Bs1);                        /* tile 11 */           \
        __syncthreads();                                                      \
    }

#define DECL_LDS_DB()                                                         \
    __shared__ __align__(16) __hip_bfloat16 As0[128][64];                     \
    __shared__ __align__(16) __hip_bfloat16 Bs0[128][64];                     \
    __shared__ __align__(16) __hip_bfloat16 As1[128][64];                     \
    __shared__ __align__(16) __hip_bfloat16 Bs1[128][64];

#define DECL_ACC()                                                            \
    f32x4 acc[4][4];                                                          \
    _Pragma("unroll") for (int i = 0; i < 4; ++i)                             \
        _Pragma("unroll") for (int j = 0; j < 4; ++j)                         \
            _Pragma("unroll") for (int e = 0; e < 4; ++e) acc[i][j][e] = 0.0f;

// ---------------------------------------------------------------------------
// P-ALL: wct / const / w1t / out_init / conv_q / zero-smU fused.
// (build_groups removed — segment-max is now atomic-fused into the ts GEMM.)
//   [0,1152)      prep_wct
//   [1152,1200)   prep_const
//   [1200,1488)   prep_w1t
//   [1488,1490)   out_init
//   [1490,11090)  conv_q
//   [11090,12050) zero smU (re-zeroed EVERY call: graph-replay safe)
// ---------------------------------------------------------------------------
__global__ __launch_bounds__(256) void prep_all(
    const float* __restrict__ answer, const float* __restrict__ W_p,
    const float* __restrict__ b_p, const float* __restrict__ W_t,
    const float* __restrict__ b_t, const float* __restrict__ W1,
    const float* __restrict__ qps, const float* __restrict__ mask,
    const float* __restrict__ b2,
    __hip_bfloat16* __restrict__ Wpe_nat, __hip_bfloat16* __restrict__ Wbig,
    float* __restrict__ c_p, float* __restrict__ c_t,
    __hip_bfloat16* __restrict__ qb, __hip_bfloat16* __restrict__ W1at,
    __hip_bfloat16* __restrict__ W1bt, unsigned int* __restrict__ smU,
    float* __restrict__ out)
{
    __shared__ float lds[64][65];
    __shared__ float a_s[64];
    __shared__ float red2[2][4][64];

    const int bid = blockIdx.x;
    const int tid = threadIdx.x;

    if (bid < 1152) {
        const int n0 = (bid % 24) * 64;
        const int k0 = ((bid / 24) % 12) * 64;
        const int b  = bid / 288;
        if (tid < 64) a_s[tid] = answer[((size_t)b * L_ + (L_ - 1)) * D_ + k0 + tid];
        __syncthreads();
        if (n0 < D_) {
#pragma unroll
            for (int i = 0; i < 16; ++i) {
                int k = (tid >> 6) + i * 4;
                int n = tid & 63;
                float v = W_p[(size_t)(D_ + k0 + k) * D_ + n0 + n] +
                          a_s[k] * W_p[(size_t)(2 * D_ + k0 + k) * D_ + n0 + n];
                Wpe_nat[(size_t)b * D_ * D_ + (size_t)(k0 + k) * D_ + n0 + n] =
                    __float2bfloat16(v);
            }
        } else {
            const int nn0 = n0 - D_;
#pragma unroll
            for (int i = 0; i < 16; ++i) {
                int k = (tid >> 6) + i * 4;
                int n = tid & 63;
                lds[k][n] = W_t[(size_t)(D_ + k0 + k) * D_ + nn0 + n] +
                            a_s[k] * W_t[(size_t)(2 * D_ + k0 + k) * D_ + nn0 + n];
            }
            __syncthreads();
#pragma unroll
            for (int j = 0; j < 16; ++j) {
                int n = (tid >> 6) + j * 4;
                int kk = tid & 63;
                Wbig[((size_t)b * NC_ + n0 + n) * D_ + k0 + kk] =
                    __float2bfloat16(lds[kk][n]);
            }
        }
    } else if (bid < 1200) {
        const int local = bid - 1152;
        const int b = local / 12;
        const int d = (local % 12) * 64 + (tid & 63);
        const int ks = tid >> 6;
        const float* a = answer + ((size_t)b * L_ + (L_ - 1)) * D_;
        float sp = 0.f, st = 0.f;
#pragma unroll 4
        for (int k = ks; k < D_; k += 4) {
            float av = a[k];
            sp += av * W_p[(size_t)k * D_ + d];
            st += av * W_t[(size_t)k * D_ + d];
        }
        red2[0][ks][tid & 63] = sp;
        red2[1][ks][tid & 63] = st;
        __syncthreads();
        if (ks == 0) {
            float s1 = b_p[d], s2 = b_t[d];
#pragma unroll
            for (int i = 0; i < 4; ++i) {
                s1 += red2[0][i][tid & 63];
                s2 += red2[1][i][tid & 63];
            }
            c_p[b * D_ + d] = s1;
            c_t[b * D_ + d] = s2;
        }
    } else if (bid < 1488) {
        const int local = bid - 1200;
        const int n0 = (local % 12) * 64;
        const int k0 = (local / 12) * 64;
#pragma unroll
        for (int i = 0; i < 16; ++i) {
            int k = (tid >> 6) + i * 4;
            int n = tid & 63;
            lds[k][n] = W1[(size_t)(k0 + k) * D_ + n0 + n];
        }
        __syncthreads();
        __hip_bfloat16* dst = (k0 < D_) ? W1at : W1bt;
        const int kk0 = (k0 < D_) ? k0 : k0 - D_;
#pragma unroll
        for (int j = 0; j < 16; ++j) {
            int n = (tid >> 6) + j * 4;
            int kk = tid & 63;
            dst[(size_t)(n0 + n) * D_ + kk0 + kk] = __float2bfloat16(lds[kk][n]);
        }
    } else if (bid < 1490) {
        int bp = (bid - 1488) * 256 + tid;
        if (bp < B_ * P_) {
            float s = 0.f;
#pragma unroll 8
            for (int t = 0; t < TPP_; ++t) s += mask[(size_t)bp * TPP_ + t];
            out[bp] = s * b2[0];
        }
    } else if (bid < 11090) {
        size_t base = ((size_t)(bid - 1490) * 256 + tid) * 8;
        int b = (int)(base / ((size_t)T_ * D_));
        size_t off = base % ((size_t)T_ * D_);
        const float4* src = reinterpret_cast<const float4*>(
            qps + ((size_t)b * L_ + (L_ - 1)) * (size_t)T_ * D_ + off);
        float4 v0 = src[0], v1 = src[1];
        bf16x8 o;
        o[0] = (short)f2bf(v0.x); o[1] = (short)f2bf(v0.y);
        o[2] = (short)f2bf(v0.z); o[3] = (short)f2bf(v0.w);
        o[4] = (short)f2bf(v1.x); o[5] = (short)f2bf(v1.y);
        o[6] = (short)f2bf(v1.z); o[7] = (short)f2bf(v1.w);
        *reinterpret_cast<bf16x8*>(&qb[base]) = o;
    } else {
        // zero smU (encoded -inf == 0)
        size_t base = ((size_t)(bid - 11090) * 256 + tid) * 8;
        uint4 z = {0u, 0u, 0u, 0u};
        *reinterpret_cast<uint4*>(&smU[base]) = z;
        *reinterpret_cast<uint4*>(&smU[base + 4]) = z;
    }
}

// ---------------------------------------------------------------------------
// FUSED K2: [0,1200) ts-GEMM with ATOMIC SEGMENT-MAX epilogue (ts never
// materialized); [1200,1344) gemm_c1; [1344,1392) prep_cc.
// ---------------------------------------------------------------------------
__global__ __launch_bounds__(256) void fused_ts_c1(
    const __hip_bfloat16* __restrict__ qb, __hip_bfloat16* __restrict__ Wbig,
    const float* __restrict__ c_t, const int* __restrict__ tids,
    unsigned int* __restrict__ smU,
    const __hip_bfloat16* __restrict__ W1at,
    const __hip_bfloat16* __restrict__ Wpe_nat,
    const float* __restrict__ c_p, const float* __restrict__ W1,
    const float* __restrict__ b1, float* __restrict__ cc)
{
    DECL_LDS_DB();
    __shared__ float red[4][64];
    const int bid = blockIdx.x;
    const int tid = threadIdx.x;
    const int lane = tid & 63, w = tid >> 6;
    const int wm = w & 1, wn = w >> 1;

    if (bid < 1200) {
        const int swz = (bid & 7) * 150 + (bid >> 3);
        const int tn = swz % 6;
        const int tmb = swz / 6;
        const int tm = tmb % 50, b = tmb / 50;
        DECL_ACC();
        const __hip_bfloat16* Ag = qb + (size_t)b * T_ * D_ + (size_t)tm * 128 * D_;
        const __hip_bfloat16* Bg =
            Wbig + (size_t)b * NC_ * D_ + (size_t)(D_ + tn * 128) * D_;
        MFMA_LOOP_PIPE(Ag, Bg);

        // ---- atomic segment-max epilogue: wave's 64 rows == one passage ----
        const int p = tm * 2 + wm;
        const int g = tids[b * P_ + p];
        unsigned int* smb = smU + ((size_t)(b * G_ + g) * TPP_) * D_;
        const int h = lane >> 4;
#pragma unroll
        for (int ni = 0; ni < 4; ++ni) {
            int col = tn * 128 + wn * 64 + ni * 16 + (lane & 15);
            float cv = c_t[b * D_ + col];
#pragma unroll
            for (int mi = 0; mi < 4; ++mi)
#pragma unroll
                for (int e = 0; e < 4; ++e) {
                    int t = mi * 16 + h * 4 + e;   // token within passage
                    atomicMax(&smb[(size_t)t * D_ + col],
                              fenc(acc[mi][ni][e] + cv));
                }
        }
    } else if (bid < 1344) {
        const int local = bid - 1200;
        const int tm = local % 6, tn = (local / 6) % 6, b = local / 36;
        DECL_ACC();
        const __hip_bfloat16* Ag = W1at + (size_t)tm * 128 * D_;
        const __hip_bfloat16* Bg =
            Wpe_nat + (size_t)b * D_ * D_ + (size_t)tn * 128 * D_;
        MFMA_LOOP_PIPE(Ag, Bg);
#pragma unroll
        for (int mi = 0; mi < 4; ++mi)
#pragma unroll
            for (int ni = 0; ni < 4; ++ni) {
                int col = tn * 128 + wn * 64 + ni * 16 + (lane & 15);
                int row = tm * 128 + wm * 64 + mi * 16 + (lane >> 4) * 4;
#pragma unroll
                for (int e = 0; e < 4; ++e)
                    Wbig[(size_t)b * NC_ * D_ + (size_t)(row + e) * D_ + col] =
                        __float2bfloat16(acc[mi][ni][e]);
            }
    } else {
        const int local = bid - 1344;
        const int b = local / 12;
        const int n = (local % 12) * 64 + (tid & 63);
        const int ks = tid >> 6;
        float s = 0.f;
#pragma unroll 4
        for (int d = ks; d < D_; d += 4)
            s += c_p[b * D_ + d] * W1[(size_t)d * D_ + n];
        red[ks][tid & 63] = s;
        __syncthreads();
        if (ks == 0) {
            float tot = b1[n];
#pragma unroll
            for (int i = 0; i < 4; ++i) tot += red[i][tid & 63];
            cc[b * D_ + n] = tot;
        }
    }
}

// ---------------------------------------------------------------------------
// K3: decode smU (monotonic uint) -> sm (bf16).  960 blocks, 8 elem/thread.
// ---------------------------------------------------------------------------
__global__ __launch_bounds__(256) void sm_convert(
    const unsigned int* __restrict__ smU, __hip_bfloat16* __restrict__ sm)
{
    size_t base = ((size_t)blockIdx.x * 256 + threadIdx.x) * 8;
    uint4 u0 = *reinterpret_cast<const uint4*>(&smU[base]);
    uint4 u1 = *reinterpret_cast<const uint4*>(&smU[base + 4]);
    bf16x8 o;
    o[0] = (short)f2bf(fdec(u0.x)); o[1] = (short)f2bf(fdec(u0.y));
    o[2] = (short)f2bf(fdec(u0.z)); o[3] = (short)f2bf(fdec(u0.w));
    o[4] = (short)f2bf(fdec(u1.x)); o[5] = (short)f2bf(fdec(u1.y));
    o[6] = (short)f2bf(fdec(u1.z)); o[7] = (short)f2bf(fdec(u1.w));
    *reinterpret_cast<bf16x8*>(&sm[base]) = o;
}

// ---------------------------------------------------------------------------
// K4: smW = sm @ W1bt^T  (120 blocks, XCD-swizzled: 120 = 8*15)
// ---------------------------------------------------------------------------
__global__ __launch_bounds__(256) void gemm_smw(
    const __hip_bfloat16* __restrict__ sm, const __hip_bfloat16* __restrict__ W1bt,
    __hip_bfloat16* __restrict__ smW)
{
    const int swz = (blockIdx.x & 7) * 15 + (blockIdx.x >> 3);
    const int tn = swz % 6, tm = swz / 6;
    DECL_LDS_DB();
    const int tid = threadIdx.x;
    const int lane = tid & 63, w = tid >> 6;
    const int wm = w & 1, wn = w >> 1;
    DECL_ACC();

    const __hip_bfloat16* Ag = sm + (size_t)tm * 128 * D_;
    const __hip_bfloat16* Bg = W1bt + (size_t)tn * 128 * D_;
    MFMA_LOOP_PIPE(Ag, Bg);

#pragma unroll
    for (int mi = 0; mi < 4; ++mi)
#pragma unroll
        for (int ni = 0; ni < 4; ++ni) {
            int col = tn * 128 + wn * 64 + ni * 16 + (lane & 15);
            int rb  = tm * 128 + wm * 64 + mi * 16 + (lane >> 4) * 4;
#pragma unroll
            for (int e = 0; e < 4; ++e)
                smW[(size_t)(rb + e) * D_ + col] = __float2bfloat16(acc[mi][ni][e]);
        }
}

// ---------------------------------------------------------------------------
// K5: fused  acc = qb @ Wbig[b][0..768]^T ; v = relu(acc + cc + smW[g])
//     rowdot = v . W2 ; out[b][p] += sum_t mask * rowdot
//     1200 blocks 1D, XCD-swizzled (r12 verbatim).
// ---------------------------------------------------------------------------
__global__ __launch_bounds__(256) void gemm_fin(
    const __hip_bfloat16* __restrict__ qb, const __hip_bfloat16* __restrict__ Wbig,
    const float* __restrict__ cc, const __hip_bfloat16* __restrict__ smW,
    const int* __restrict__ tids, const float* __restrict__ W2,
    const float* __restrict__ mask, float* __restrict__ out)
{
    const int swz = (blockIdx.x & 7) * 150 + (blockIdx.x >> 3);
    const int tn = swz % 6;
    const int tmb = swz / 6;
    const int tm = tmb % 50, b = tmb / 50;
    DECL_LDS_DB();
    __shared__ float rowsum[2][128];

    const int tid = threadIdx.x;
    const int lane = tid & 63, w = tid >> 6;
    const int wm = w & 1, wn = w >> 1;
    DECL_ACC();

    const __hip_bfloat16* Ag = qb + (size_t)b * T_ * D_ + (size_t)tm * 128 * D_;
    const __hip_bfloat16* Bg = Wbig + (size_t)b * NC_ * D_ + (size_t)tn * 128 * D_;
    MFMA_LOOP_PIPE(Ag, Bg);

    const int p = tm * 2 + wm;
    const int g = tids[b * P_ + p];
    const __hip_bfloat16* smWg = smW + ((size_t)(b * G_ + g) * TPP_) * D_;
    const int h = lane >> 4;

    float rs[4][4];
#pragma unroll
    for (int mi = 0; mi < 4; ++mi)
#pragma unroll
        for (int e = 0; e < 4; ++e) rs[mi][e] = 0.f;

#pragma unroll
    for (int ni = 0; ni < 4; ++ni) {
        int col = tn * 128 + wn * 64 + ni * 16 + (lane & 15);
        float ccv = cc[b * D_ + col];
        float w2v = W2[col];
#pragma unroll
        for (int mi = 0; mi < 4; ++mi)
#pragma unroll
            for (int e = 0; e < 4; ++e) {
                int trow = mi * 16 + h * 4 + e;
                float v = acc[mi][ni][e] + ccv +
                          bfu2f(*reinterpret_cast<const unsigned short*>(
                              &smWg[(size_t)trow * D_ + col]));
                rs[mi][e] += fmaxf(v, 0.f) * w2v;
            }
    }
#pragma unroll
    for (int off = 8; off >= 1; off >>= 1)
#pragma unroll
        for (int mi = 0; mi < 4; ++mi)
#pragma unroll
            for (int e = 0; e < 4; ++e) rs[mi][e] += __shfl_xor(rs[mi][e], off);

    if ((lane & 15) == 0) {
#pragma unroll
        for (int mi = 0; mi < 4; ++mi)
#pragma unroll
            for (int e = 0; e < 4; ++e)
                rowsum[wn][wm * 64 + mi * 16 + h * 4 + e] = rs[mi][e];
    }
    __syncthreads();

    if (tid < 128) {
        int pp = tid >> 6, t = tid & 63;
        float v = (rowsum[0][tid] + rowsum[1][tid]) *
                  mask[((size_t)b * P_ + tm * 2 + pp) * TPP_ + t];
#pragma unroll
        for (int off = 32; off >= 1; off >>= 1) v += __shfl_xor(v, off);
        if (t == 0) atomicAdd(&out[b * P_ + tm * 2 + pp], v);
    }
}

// ---------------------------------------------------------------------------
extern "C" void kernel_launch(void* const* d_in, const int* in_sizes, int n_in,
                              void* d_out, int out_size, void* d_ws, size_t ws_size,
                              hipStream_t stream)
{
    const float* answer = (const float*)d_in[0];
    const float* qps    = (const float*)d_in[1];
    const float* mask   = (const float*)d_in[2];
    const int*   tids   = (const int*)d_in[3];
    // d_in[4] = fusion_scores: unused by the reference
    const float* W_p = (const float*)d_in[5];
    const float* b_p = (const float*)d_in[6];
    const float* W_t = (const float*)d_in[7];
    const float* b_t = (const float*)d_in[8];
    const float* W1  = (const float*)d_in[9];
    const float* b1  = (const float*)d_in[10];
    const float* W2  = (const float*)d_in[11];
    const float* b2  = (const float*)d_in[12];
    float* out = (float*)d_out;

    char* ws = (char*)d_ws;
    __hip_bfloat16* Wpe_nat = (__hip_bfloat16*)ws; ws += (size_t)B_ * D_ * D_ * 2;
    __hip_bfloat16* Wbig    = (__hip_bfloat16*)ws; ws += (size_t)B_ * NC_ * D_ * 2;
    float* c_p = (float*)ws;                   ws += (size_t)B_ * D_ * 4;
    float* c_t = (float*)ws;                   ws += (size_t)B_ * D_ * 4;
    float* cc  = (float*)ws;                   ws += (size_t)B_ * D_ * 4;
    __hip_bfloat16* qb = (__hip_bfloat16*)ws;  ws += (size_t)B_ * T_ * D_ * 2;   // 39.3 MB
    unsigned int* smU = (unsigned int*)ws;     ws += (size_t)B_ * G_ * TPP_ * D_ * 4; // 7.86 MB
    __hip_bfloat16* sm = (__hip_bfloat16*)ws;  ws += (size_t)B_ * G_ * TPP_ * D_ * 2;
    __hip_bfloat16* smW = (__hip_bfloat16*)ws; ws += (size_t)B_ * G_ * TPP_ * D_ * 2;
    __hip_bfloat16* W1at = (__hip_bfloat16*)ws; ws += (size_t)D_ * D_ * 2;
    __hip_bfloat16* W1bt = (__hip_bfloat16*)ws; ws += (size_t)D_ * D_ * 2;

    prep_all<<<12050, 256, 0, stream>>>(
        answer, W_p, b_p, W_t, b_t, W1, qps, mask, b2,
        Wpe_nat, Wbig, c_p, c_t, qb, W1at, W1bt, smU, out);
    fused_ts_c1<<<1392, 256, 0, stream>>>(
        qb, Wbig, c_t, tids, smU, W1at, Wpe_nat, c_p, W1, b1, cc);
    sm_convert<<<960, 256, 0, stream>>>(smU, sm);
    gemm_smw<<<120, 256, 0, stream>>>(sm, W1bt, smW);
    gemm_fin<<<1200, 256, 0, stream>>>(
        qb, Wbig, cc, smW, tids, W2, mask, out);
}

// Round 16
// 165.490 us; speedup vs baseline: 1.2754x; 1.0565x over previous
//
#include <hip/hip_runtime.h>
#include <hip/hip_bf16.h>

#define B_ 4
#define L_ 2
#define P_ 100
#define TPP_ 64
#define D_ 768
#define G_ 10
#define T_ (P_ * TPP_)   // 6400
#define NC_ (2 * D_)     // 1536

typedef __attribute__((ext_vector_type(8))) short bf16x8;
typedef __attribute__((ext_vector_type(4))) float f32x4;

__device__ __forceinline__ unsigned short f2bf(float f) {
    __hip_bfloat16 h = __float2bfloat16(f);
    return *reinterpret_cast<unsigned short*>(&h);
}
__device__ __forceinline__ float bfu2f(unsigned short u) {
    return __uint_as_float(((unsigned int)u) << 16);
}

__device__ __forceinline__ void gload_lds16(const void* g, void* l) {
    __builtin_amdgcn_global_load_lds(
        (const __attribute__((address_space(1))) void*)g,
        (__attribute__((address_space(3))) void*)l, 16, 0, 0);
}

#define SBAR()   __builtin_amdgcn_s_barrier()
#define SCHEDB() __builtin_amdgcn_sched_barrier(0)
#define VMCNT4() asm volatile("s_waitcnt vmcnt(4)" ::: "memory")
#define VMCNT0() asm volatile("s_waitcnt vmcnt(0)" ::: "memory")

// Monotonic float<->uint transform for atomicMax segment-max (validated r15).
__device__ __forceinline__ unsigned int fenc(float v) {
    unsigned int bits = __float_as_uint(v);
    return bits ^ (unsigned int)(((int)bits >> 31) | 0x80000000);
}
__device__ __forceinline__ float fdec(unsigned int k) {
    unsigned int bits = (k & 0x80000000u) ? (k ^ 0x80000000u) : ~k;
    return __uint_as_float(bits);
}

// ---------------------------------------------------------------------------
// r16: 8 waves (512 thr) on the same 128x128/BK=64 tile. Waves 2m x 4n
// (wn covers 32 cols, acc[4][2]). Same 64 KB LDS, same 2 barriers/tile as
// the validated r12 loop -> 2 blocks/CU x 8 waves = 16 waves/CU (vs 8).
// Per thread per tile: 2 A-loads + 2 B-loads = 4 -> steady-state vmcnt(4).
// Both-sides 8x16B-slot swizzle unchanged (r6-r15).
// ---------------------------------------------------------------------------
__device__ __forceinline__ void stage64(
    const __hip_bfloat16* __restrict__ Ag, const __hip_bfloat16* __restrict__ Bg,
    int k0, __hip_bfloat16 (*As)[64], __hip_bfloat16 (*Bs)[64],
    int w, int row_l, int soff)
{
#pragma unroll
    for (int j = 0; j < 2; ++j) {
        int r = w * 16 + j * 8 + row_l;   // r&7 == row_l; 8 waves cover 128 rows
        gload_lds16(Ag + (size_t)r * D_ + k0 + soff, &As[w * 16 + j * 8][0]);
        gload_lds16(Bg + (size_t)r * D_ + k0 + soff, &Bs[w * 16 + j * 8][0]);
    }
}

__device__ __forceinline__ void mfma_step64(
    __hip_bfloat16 (*As)[64], __hip_bfloat16 (*Bs)[64],
    int rr, int h, int wm, int wn, f32x4 acc[4][2])
{
#pragma unroll
    for (int ks = 0; ks < 2; ++ks) {
        const int rsl = (((ks << 2) + h) ^ (rr & 7)) << 3;
        bf16x8 af[4], bfr[2];
#pragma unroll
        for (int mi = 0; mi < 4; ++mi)
            af[mi] = *reinterpret_cast<const bf16x8*>(
                &As[wm * 64 + mi * 16 + rr][rsl]);
#pragma unroll
        for (int ni = 0; ni < 2; ++ni)
            bfr[ni] = *reinterpret_cast<const bf16x8*>(
                &Bs[wn * 32 + ni * 16 + rr][rsl]);
#pragma unroll
        for (int mi = 0; mi < 4; ++mi)
#pragma unroll
            for (int ni = 0; ni < 2; ++ni)
                acc[mi][ni] = __builtin_amdgcn_mfma_f32_16x16x32_bf16(
                    af[mi], bfr[ni], acc[mi][ni], 0, 0, 0);
    }
}

#define MFMA_STEP_P(As, Bs)                                                   \
    __builtin_amdgcn_s_setprio(1);                                            \
    mfma_step64(As, Bs, rr, h, wm, wn, acc);                                  \
    __builtin_amdgcn_s_setprio(0);

// T4 counted-vmcnt pipeline (r12 structure, vmcnt re-derived for 4 loads).
#define MFMA_LOOP_PIPE(Ag, Bg)                                                \
    {                                                                         \
        const int rr = lane & 15, h = lane >> 4;                              \
        const int row_l = lane >> 3;                                          \
        const int soff = ((lane & 7) ^ row_l) << 3;                           \
        stage64((Ag), (Bg), 0, As0, Bs0, w, row_l, soff);                     \
        stage64((Ag), (Bg), 64, As1, Bs1, w, row_l, soff);                    \
        SCHEDB();                                                             \
        for (int t = 0; t < 10; t += 2) {                                     \
            VMCNT4(); SBAR(); SCHEDB();                                       \
            MFMA_STEP_P(As0, Bs0);                                            \
            SCHEDB(); SBAR(); SCHEDB();                                       \
            stage64((Ag), (Bg), (t + 2) * 64, As0, Bs0, w, row_l, soff);      \
            SCHEDB();                                                         \
            VMCNT4(); SBAR(); SCHEDB();                                       \
            MFMA_STEP_P(As1, Bs1);                                            \
            SCHEDB(); SBAR(); SCHEDB();                                       \
            stage64((Ag), (Bg), (t + 3) * 64, As1, Bs1, w, row_l, soff);      \
            SCHEDB();                                                         \
        }                                                                     \
        VMCNT4(); SBAR(); SCHEDB();                                           \
        MFMA_STEP_P(As0, Bs0);                        /* tile 10 */           \
        SCHEDB();                                                             \
        VMCNT0(); SBAR(); SCHEDB();                                           \
        MFMA_STEP_P(As1, Bs1);                        /* tile 11 */           \
        __syncthreads();                                                      \
    }

#define DECL_LDS_DB()                                                         \
    __shared__ __align__(16) __hip_bfloat16 As0[128][64];                     \
    __shared__ __align__(16) __hip_bfloat16 Bs0[128][64];                     \
    __shared__ __align__(16) __hip_bfloat16 As1[128][64];                     \
    __shared__ __align__(16) __hip_bfloat16 Bs1[128][64];

#define DECL_ACC()                                                            \
    f32x4 acc[4][2];                                                          \
    _Pragma("unroll") for (int i = 0; i < 4; ++i)                             \
        _Pragma("unroll") for (int j = 0; j < 2; ++j)                         \
            _Pragma("unroll") for (int e = 0; e < 4; ++e) acc[i][j][e] = 0.0f;

// ---------------------------------------------------------------------------
// P-ALL (r15 verbatim): wct / const / w1t / out_init / conv_q / zero-smU.
// ---------------------------------------------------------------------------
__global__ __launch_bounds__(256) void prep_all(
    const float* __restrict__ answer, const float* __restrict__ W_p,
    const float* __restrict__ b_p, const float* __restrict__ W_t,
    const float* __restrict__ b_t, const float* __restrict__ W1,
    const float* __restrict__ qps, const float* __restrict__ mask,
    const float* __restrict__ b2,
    __hip_bfloat16* __restrict__ Wpe_nat, __hip_bfloat16* __restrict__ Wbig,
    float* __restrict__ c_p, float* __restrict__ c_t,
    __hip_bfloat16* __restrict__ qb, __hip_bfloat16* __restrict__ W1at,
    __hip_bfloat16* __restrict__ W1bt, unsigned int* __restrict__ smU,
    float* __restrict__ out)
{
    __shared__ float lds[64][65];
    __shared__ float a_s[64];
    __shared__ float red2[2][4][64];

    const int bid = blockIdx.x;
    const int tid = threadIdx.x;

    if (bid < 1152) {
        const int n0 = (bid % 24) * 64;
        const int k0 = ((bid / 24) % 12) * 64;
        const int b  = bid / 288;
        if (tid < 64) a_s[tid] = answer[((size_t)b * L_ + (L_ - 1)) * D_ + k0 + tid];
        __syncthreads();
        if (n0 < D_) {
#pragma unroll
            for (int i = 0; i < 16; ++i) {
                int k = (tid >> 6) + i * 4;
                int n = tid & 63;
                float v = W_p[(size_t)(D_ + k0 + k) * D_ + n0 + n] +
                          a_s[k] * W_p[(size_t)(2 * D_ + k0 + k) * D_ + n0 + n];
                Wpe_nat[(size_t)b * D_ * D_ + (size_t)(k0 + k) * D_ + n0 + n] =
                    __float2bfloat16(v);
            }
        } else {
            const int nn0 = n0 - D_;
#pragma unroll
            for (int i = 0; i < 16; ++i) {
                int k = (tid >> 6) + i * 4;
                int n = tid & 63;
                lds[k][n] = W_t[(size_t)(D_ + k0 + k) * D_ + nn0 + n] +
                            a_s[k] * W_t[(size_t)(2 * D_ + k0 + k) * D_ + nn0 + n];
            }
            __syncthreads();
#pragma unroll
            for (int j = 0; j < 16; ++j) {
                int n = (tid >> 6) + j * 4;
                int kk = tid & 63;
                Wbig[((size_t)b * NC_ + n0 + n) * D_ + k0 + kk] =
                    __float2bfloat16(lds[kk][n]);
            }
        }
    } else if (bid < 1200) {
        const int local = bid - 1152;
        const int b = local / 12;
        const int d = (local % 12) * 64 + (tid & 63);
        const int ks = tid >> 6;
        const float* a = answer + ((size_t)b * L_ + (L_ - 1)) * D_;
        float sp = 0.f, st = 0.f;
#pragma unroll 4
        for (int k = ks; k < D_; k += 4) {
            float av = a[k];
            sp += av * W_p[(size_t)k * D_ + d];
            st += av * W_t[(size_t)k * D_ + d];
        }
        red2[0][ks][tid & 63] = sp;
        red2[1][ks][tid & 63] = st;
        __syncthreads();
        if (ks == 0) {
            float s1 = b_p[d], s2 = b_t[d];
#pragma unroll
            for (int i = 0; i < 4; ++i) {
                s1 += red2[0][i][tid & 63];
                s2 += red2[1][i][tid & 63];
            }
            c_p[b * D_ + d] = s1;
            c_t[b * D_ + d] = s2;
        }
    } else if (bid < 1488) {
        const int local = bid - 1200;
        const int n0 = (local % 12) * 64;
        const int k0 = (local / 12) * 64;
#pragma unroll
        for (int i = 0; i < 16; ++i) {
            int k = (tid >> 6) + i * 4;
            int n = tid & 63;
            lds[k][n] = W1[(size_t)(k0 + k) * D_ + n0 + n];
        }
        __syncthreads();
        __hip_bfloat16* dst = (k0 < D_) ? W1at : W1bt;
        const int kk0 = (k0 < D_) ? k0 : k0 - D_;
#pragma unroll
        for (int j = 0; j < 16; ++j) {
            int n = (tid >> 6) + j * 4;
            int kk = tid & 63;
            dst[(size_t)(n0 + n) * D_ + kk0 + kk] = __float2bfloat16(lds[kk][n]);
        }
    } else if (bid < 1490) {
        int bp = (bid - 1488) * 256 + tid;
        if (bp < B_ * P_) {
            float s = 0.f;
#pragma unroll 8
            for (int t = 0; t < TPP_; ++t) s += mask[(size_t)bp * TPP_ + t];
            out[bp] = s * b2[0];
        }
    } else if (bid < 11090) {
        size_t base = ((size_t)(bid - 1490) * 256 + tid) * 8;
        int b = (int)(base / ((size_t)T_ * D_));
        size_t off = base % ((size_t)T_ * D_);
        const float4* src = reinterpret_cast<const float4*>(
            qps + ((size_t)b * L_ + (L_ - 1)) * (size_t)T_ * D_ + off);
        float4 v0 = src[0], v1 = src[1];
        bf16x8 o;
        o[0] = (short)f2bf(v0.x); o[1] = (short)f2bf(v0.y);
        o[2] = (short)f2bf(v0.z); o[3] = (short)f2bf(v0.w);
        o[4] = (short)f2bf(v1.x); o[5] = (short)f2bf(v1.y);
        o[6] = (short)f2bf(v1.z); o[7] = (short)f2bf(v1.w);
        *reinterpret_cast<bf16x8*>(&qb[base]) = o;
    } else {
        size_t base = ((size_t)(bid - 11090) * 256 + tid) * 8;
        uint4 z = {0u, 0u, 0u, 0u};
        *reinterpret_cast<uint4*>(&smU[base]) = z;
        *reinterpret_cast<uint4*>(&smU[base + 4]) = z;
    }
}

// ---------------------------------------------------------------------------
// FUSED K2 (512 thr): [0,1200) ts-GEMM + atomic segment-max epilogue;
// [1200,1344) gemm_c1; [1344,1392) prep_cc (8-way K split).
// ---------------------------------------------------------------------------
__global__ __launch_bounds__(512) void fused_ts_c1(
    const __hip_bfloat16* __restrict__ qb, __hip_bfloat16* __restrict__ Wbig,
    const float* __restrict__ c_t, const int* __restrict__ tids,
    unsigned int* __restrict__ smU,
    const __hip_bfloat16* __restrict__ W1at,
    const __hip_bfloat16* __restrict__ Wpe_nat,
    const float* __restrict__ c_p, const float* __restrict__ W1,
    const float* __restrict__ b1, float* __restrict__ cc)
{
    DECL_LDS_DB();
    __shared__ float red[8][64];
    const int bid = blockIdx.x;
    const int tid = threadIdx.x;
    const int lane = tid & 63, w = tid >> 6;
    const int wm = w & 1, wn = w >> 1;   // 2m x 4n

    if (bid < 1200) {
        const int swz = (bid & 7) * 150 + (bid >> 3);
        const int tn = swz % 6;
        const int tmb = swz / 6;
        const int tm = tmb % 50, b = tmb / 50;
        DECL_ACC();
        const __hip_bfloat16* Ag = qb + (size_t)b * T_ * D_ + (size_t)tm * 128 * D_;
        const __hip_bfloat16* Bg =
            Wbig + (size_t)b * NC_ * D_ + (size_t)(D_ + tn * 128) * D_;
        MFMA_LOOP_PIPE(Ag, Bg);

        // atomic segment-max epilogue (validated r15)
        const int p = tm * 2 + wm;
        const int g = tids[b * P_ + p];
        unsigned int* smb = smU + ((size_t)(b * G_ + g) * TPP_) * D_;
        const int h = lane >> 4;
#pragma unroll
        for (int ni = 0; ni < 2; ++ni) {
            int col = tn * 128 + wn * 32 + ni * 16 + (lane & 15);
            float cv = c_t[b * D_ + col];
#pragma unroll
            for (int mi = 0; mi < 4; ++mi)
#pragma unroll
                for (int e = 0; e < 4; ++e) {
                    int t = mi * 16 + h * 4 + e;
                    atomicMax(&smb[(size_t)t * D_ + col],
                              fenc(acc[mi][ni][e] + cv));
                }
        }
    } else if (bid < 1344) {
        const int local = bid - 1200;
        const int tm = local % 6, tn = (local / 6) % 6, b = local / 36;
        DECL_ACC();
        const __hip_bfloat16* Ag = W1at + (size_t)tm * 128 * D_;
        const __hip_bfloat16* Bg =
            Wpe_nat + (size_t)b * D_ * D_ + (size_t)tn * 128 * D_;
        MFMA_LOOP_PIPE(Ag, Bg);
#pragma unroll
        for (int mi = 0; mi < 4; ++mi)
#pragma unroll
            for (int ni = 0; ni < 2; ++ni) {
                int col = tn * 128 + wn * 32 + ni * 16 + (lane & 15);
                int row = tm * 128 + wm * 64 + mi * 16 + (lane >> 4) * 4;
#pragma unroll
                for (int e = 0; e < 4; ++e)
                    Wbig[(size_t)b * NC_ * D_ + (size_t)(row + e) * D_ + col] =
                        __float2bfloat16(acc[mi][ni][e]);
            }
    } else {
        const int local = bid - 1344;
        const int b = local / 12;
        const int n = (local % 12) * 64 + (tid & 63);
        const int ks = tid >> 6;                 // 0..7
        float s = 0.f;
#pragma unroll 4
        for (int d = ks; d < D_; d += 8)
            s += c_p[b * D_ + d] * W1[(size_t)d * D_ + n];
        red[ks][tid & 63] = s;
        __syncthreads();
        if (ks == 0) {
            float tot = b1[n];
#pragma unroll
            for (int i = 0; i < 8; ++i) tot += red[i][tid & 63];
            cc[b * D_ + n] = tot;
        }
    }
}

// ---------------------------------------------------------------------------
// K3: decode smU -> sm (bf16).  960 blocks, 8 elem/thread.
// ---------------------------------------------------------------------------
__global__ __launch_bounds__(256) void sm_convert(
    const unsigned int* __restrict__ smU, __hip_bfloat16* __restrict__ sm)
{
    size_t base = ((size_t)blockIdx.x * 256 + threadIdx.x) * 8;
    uint4 u0 = *reinterpret_cast<const uint4*>(&smU[base]);
    uint4 u1 = *reinterpret_cast<const uint4*>(&smU[base + 4]);
    bf16x8 o;
    o[0] = (short)f2bf(fdec(u0.x)); o[1] = (short)f2bf(fdec(u0.y));
    o[2] = (short)f2bf(fdec(u0.z)); o[3] = (short)f2bf(fdec(u0.w));
    o[4] = (short)f2bf(fdec(u1.x)); o[5] = (short)f2bf(fdec(u1.y));
    o[6] = (short)f2bf(fdec(u1.z)); o[7] = (short)f2bf(fdec(u1.w));
    *reinterpret_cast<bf16x8*>(&sm[base]) = o;
}

// ---------------------------------------------------------------------------
// K4: smW = sm @ W1bt^T  (120 blocks, XCD-swizzled, 512 thr)
// ---------------------------------------------------------------------------
__global__ __launch_bounds__(512) void gemm_smw(
    const __hip_bfloat16* __restrict__ sm, const __hip_bfloat16* __restrict__ W1bt,
    __hip_bfloat16* __restrict__ smW)
{
    const int swz = (blockIdx.x & 7) * 15 + (blockIdx.x >> 3);
    const int tn = swz % 6, tm = swz / 6;
    DECL_LDS_DB();
    const int tid = threadIdx.x;
    const int lane = tid & 63, w = tid >> 6;
    const int wm = w & 1, wn = w >> 1;
    DECL_ACC();

    const __hip_bfloat16* Ag = sm + (size_t)tm * 128 * D_;
    const __hip_bfloat16* Bg = W1bt + (size_t)tn * 128 * D_;
    MFMA_LOOP_PIPE(Ag, Bg);

#pragma unroll
    for (int mi = 0; mi < 4; ++mi)
#pragma unroll
        for (int ni = 0; ni < 2; ++ni) {
            int col = tn * 128 + wn * 32 + ni * 16 + (lane & 15);
            int rb  = tm * 128 + wm * 64 + mi * 16 + (lane >> 4) * 4;
#pragma unroll
            for (int e = 0; e < 4; ++e)
                smW[(size_t)(rb + e) * D_ + col] = __float2bfloat16(acc[mi][ni][e]);
        }
}

// ---------------------------------------------------------------------------
// K5: fused  acc = qb @ Wbig[b][0..768]^T ; v = relu(acc + cc + smW[g])
//     rowdot = v . W2 ; out[b][p] += sum_t mask * rowdot
//     1200 blocks, 512 thr, XCD-swizzled; rowsum over 4 wn-groups.
// ---------------------------------------------------------------------------
__global__ __launch_bounds__(512) void gemm_fin(
    const __hip_bfloat16* __restrict__ qb, const __hip_bfloat16* __restrict__ Wbig,
    const float* __restrict__ cc, const __hip_bfloat16* __restrict__ smW,
    const int* __restrict__ tids, const float* __restrict__ W2,
    const float* __restrict__ mask, float* __restrict__ out)
{
    const int swz = (blockIdx.x & 7) * 150 + (blockIdx.x >> 3);
    const int tn = swz % 6;
    const int tmb = swz / 6;
    const int tm = tmb % 50, b = tmb / 50;
    DECL_LDS_DB();
    __shared__ float rowsum[4][128];

    const int tid = threadIdx.x;
    const int lane = tid & 63, w = tid >> 6;
    const int wm = w & 1, wn = w >> 1;
    DECL_ACC();

    const __hip_bfloat16* Ag = qb + (size_t)b * T_ * D_ + (size_t)tm * 128 * D_;
    const __hip_bfloat16* Bg = Wbig + (size_t)b * NC_ * D_ + (size_t)tn * 128 * D_;
    MFMA_LOOP_PIPE(Ag, Bg);

    const int p = tm * 2 + wm;
    const int g = tids[b * P_ + p];
    const __hip_bfloat16* smWg = smW + ((size_t)(b * G_ + g) * TPP_) * D_;
    const int h = lane >> 4;

    float rs[4][4];
#pragma unroll
    for (int mi = 0; mi < 4; ++mi)
#pragma unroll
        for (int e = 0; e < 4; ++e) rs[mi][e] = 0.f;

#pragma unroll
    for (int ni = 0; ni < 2; ++ni) {
        int col = tn * 128 + wn * 32 + ni * 16 + (lane & 15);
        float ccv = cc[b * D_ + col];
        float w2v = W2[col];
#pragma unroll
        for (int mi = 0; mi < 4; ++mi)
#pragma unroll
            for (int e = 0; e < 4; ++e) {
                int trow = mi * 16 + h * 4 + e;
                float v = acc[mi][ni][e] + ccv +
                          bfu2f(*reinterpret_cast<const unsigned short*>(
                              &smWg[(size_t)trow * D_ + col]));
                rs[mi][e] += fmaxf(v, 0.f) * w2v;
            }
    }
#pragma unroll
    for (int off = 8; off >= 1; off >>= 1)
#pragma unroll
        for (int mi = 0; mi < 4; ++mi)
#pragma unroll
            for (int e = 0; e < 4; ++e) rs[mi][e] += __shfl_xor(rs[mi][e], off);

    if ((lane & 15) == 0) {
        float* dst = &rowsum[wn][wm * 64];
#pragma unroll
        for (int mi = 0; mi < 4; ++mi)
#pragma unroll
            for (int e = 0; e < 4; ++e)
                dst[mi * 16 + h * 4 + e] = rs[mi][e];
    }
    __syncthreads();

    if (tid < 128) {
        int pp = tid >> 6, t = tid & 63;
        float v = (rowsum[0][tid] + rowsum[1][tid] + rowsum[2][tid] +
                   rowsum[3][tid]) *
                  mask[((size_t)b * P_ + tm * 2 + pp) * TPP_ + t];
#pragma unroll
        for (int off = 32; off >= 1; off >>= 1) v += __shfl_xor(v, off);
        if (t == 0) atomicAdd(&out[b * P_ + tm * 2 + pp], v);
    }
}

// ---------------------------------------------------------------------------
extern "C" void kernel_launch(void* const* d_in, const int* in_sizes, int n_in,
                              void* d_out, int out_size, void* d_ws, size_t ws_size,
                              hipStream_t stream)
{
    const float* answer = (const float*)d_in[0];
    const float* qps    = (const float*)d_in[1];
    const float* mask   = (const float*)d_in[2];
    const int*   tids   = (const int*)d_in[3];
    // d_in[4] = fusion_scores: unused by the reference
    const float* W_p = (const float*)d_in[5];
    const float* b_p = (const float*)d_in[6];
    const float* W_t = (const float*)d_in[7];
    const float* b_t = (const float*)d_in[8];
    const float* W1  = (const float*)d_in[9];
    const float* b1  = (const float*)d_in[10];
    const float* W2  = (const float*)d_in[11];
    const float* b2  = (const float*)d_in[12];
    float* out = (float*)d_out;

    char* ws = (char*)d_ws;
    __hip_bfloat16* Wpe_nat = (__hip_bfloat16*)ws; ws += (size_t)B_ * D_ * D_ * 2;
    __hip_bfloat16* Wbig    = (__hip_bfloat16*)ws; ws += (size_t)B_ * NC_ * D_ * 2;
    float* c_p = (float*)ws;                   ws += (size_t)B_ * D_ * 4;
    float* c_t = (float*)ws;                   ws += (size_t)B_ * D_ * 4;
    float* cc  = (float*)ws;                   ws += (size_t)B_ * D_ * 4;
    __hip_bfloat16* qb = (__hip_bfloat16*)ws;  ws += (size_t)B_ * T_ * D_ * 2;
    unsigned int* smU = (unsigned int*)ws;     ws += (size_t)B_ * G_ * TPP_ * D_ * 4;
    __hip_bfloat16* sm = (__hip_bfloat16*)ws;  ws += (size_t)B_ * G_ * TPP_ * D_ * 2;
    __hip_bfloat16* smW = (__hip_bfloat16*)ws; ws += (size_t)B_ * G_ * TPP_ * D_ * 2;
    __hip_bfloat16* W1at = (__hip_bfloat16*)ws; ws += (size_t)D_ * D_ * 2;
    __hip_bfloat16* W1bt = (__hip_bfloat16*)ws; ws += (size_t)D_ * D_ * 2;

    prep_all<<<12050, 256, 0, stream>>>(
        answer, W_p, b_p, W_t, b_t, W1, qps, mask, b2,
        Wpe_nat, Wbig, c_p, c_t, qb, W1at, W1bt, smU, out);
    fused_ts_c1<<<1392, 512, 0, stream>>>(
        qb, Wbig, c_t, tids, smU, W1at, Wpe_nat, c_p, W1, b1, cc);
    sm_convert<<<960, 256, 0, stream>>>(smU, sm);
    gemm_smw<<<120, 512, 0, stream>>>(sm, W1bt, smW);
    gemm_fin<<<1200, 512, 0, stream>>>(
        qb, Wbig, cc, smW, tids, W2, mask, out);
}